// Round 2
// baseline (1317.282 us; speedup 1.0000x reference)
//
#include <hip/hip_runtime.h>

typedef __bf16 bf16x8 __attribute__((ext_vector_type(8)));
typedef float f32x16 __attribute__((ext_vector_type(16)));
typedef unsigned short ushort8 __attribute__((ext_vector_type(8)));

// ---------- helpers ----------
__device__ __forceinline__ float gelu_exact(float x) {
    return 0.5f * x * (1.0f + erff(x * 0.70710678118654752440f));
}

// ================= CSR build =================
__global__ __launch_bounds__(256) void count_kernel(
    const int* __restrict__ tgt, const int* __restrict__ src,
    int* __restrict__ cnt_i, int* __restrict__ cnt_a, int E)
{
    int e = blockIdx.x * 256 + threadIdx.x;
    if (e < E) {
        atomicAdd(&cnt_i[tgt[e]], 1);
        atomicAdd(&cnt_a[src[e]], 1);
    }
}

__global__ __launch_bounds__(256) void scan_block(
    const int* __restrict__ cnt, int* __restrict__ offs, int* __restrict__ bsum, int N)
{
    __shared__ int s[256];
    int i = blockIdx.x * 256 + threadIdx.x;
    int v = (i < N) ? cnt[i] : 0;
    s[threadIdx.x] = v;
    __syncthreads();
    for (int d = 1; d < 256; d <<= 1) {
        int t = (threadIdx.x >= d) ? s[threadIdx.x - d] : 0;
        __syncthreads();
        s[threadIdx.x] += t;
        __syncthreads();
    }
    if (i < N) offs[i] = s[threadIdx.x] - v;   // exclusive
    if (threadIdx.x == 255) bsum[blockIdx.x] = s[255];
}

__global__ __launch_bounds__(256) void scan_bsum(int* __restrict__ bsum, int nb)
{
    __shared__ int s[256];
    int v = (threadIdx.x < nb) ? bsum[threadIdx.x] : 0;
    s[threadIdx.x] = v;
    __syncthreads();
    for (int d = 1; d < 256; d <<= 1) {
        int t = (threadIdx.x >= d) ? s[threadIdx.x - d] : 0;
        __syncthreads();
        s[threadIdx.x] += t;
        __syncthreads();
    }
    if (threadIdx.x < nb) bsum[threadIdx.x] = s[threadIdx.x] - v;  // exclusive
}

__global__ __launch_bounds__(256) void add_offs(
    int* __restrict__ offs, int* __restrict__ cursor,
    const int* __restrict__ bsum, int N, int E)
{
    int i = blockIdx.x * 256 + threadIdx.x;
    if (i < N) {
        int f = offs[i] + bsum[blockIdx.x];
        offs[i] = f;
        cursor[i] = f;
    }
    if (i == 0) offs[N] = E;
}

__global__ __launch_bounds__(256) void fill_kernel(
    const int* __restrict__ tgt, const int* __restrict__ src,
    int* __restrict__ cur_i, int* __restrict__ cur_a,
    int* __restrict__ eid_i, int* __restrict__ eid_a, int E)
{
    int e = blockIdx.x * 256 + threadIdx.x;
    if (e < E) {
        int p = atomicAdd(&cur_i[tgt[e]], 1);
        eid_i[p] = e;
        int q = atomicAdd(&cur_a[src[e]], 1);
        eid_a[q] = e;
    }
}

// ================= weight prep: f32 W[K][256] -> bf16 hi/lo, transposed [256][K] =================
struct PrepArgs {
    const float* src[7];
    unsigned short* hi[7];
    unsigned short* lo[7];
    int K[7];
    int off[8];   // block offsets (blocks per matrix = K)
};

__global__ __launch_bounds__(256) void prep_all(PrepArgs a)
{
    int b = blockIdx.x;
    int m = 0;
    #pragma unroll
    for (int i = 0; i < 6; ++i) m += (b >= a.off[i + 1]) ? 1 : 0;
    int K = a.K[m];
    int idx = (b - a.off[m]) * 256 + threadIdx.x;
    if (idx >= K * 256) return;
    int k = idx >> 8;       // N = 256
    int n = idx & 255;
    float x = a.src[m][idx];
    __bf16 h = (__bf16)x;
    __bf16 l = (__bf16)(x - (float)h);
    a.hi[m][(size_t)n * K + k] = __builtin_bit_cast(unsigned short, h);
    a.lo[m][(size_t)n * K + k] = __builtin_bit_cast(unsigned short, l);
}

// ================= fused per-target attention (unchanged) =================
__global__ __launch_bounds__(256) void fused_attn(
    const float* __restrict__ Q, const float* __restrict__ Kk, const float* __restrict__ V,
    const int* __restrict__ offs, const int* __restrict__ eids,
    const int* __restrict__ other, const float* __restrict__ nw,
    float* __restrict__ scbuf, float* __restrict__ msg, int T)
{
    int w = blockIdx.x * 4 + (threadIdx.x >> 6);
    int lane = threadIdx.x & 63;
    if (w >= T) return;
    int t = w;
    int beg = offs[t], end = offs[t + 1];
    int h = lane >> 4;

    float4 q = *(const float4*)(Q + (size_t)t * 256 + lane * 4);

    float mx = 0.f;
    for (int j = beg; j < end; ++j) {
        int e = eids[j];
        int s = other[e];
        float4 k = *(const float4*)(Kk + (size_t)s * 256 + lane * 4);
        float d = q.x * k.x + q.y * k.y + q.z * k.z + q.w * k.w;
        d += __shfl_xor(d, 1);
        d += __shfl_xor(d, 2);
        d += __shfl_xor(d, 4);
        d += __shfl_xor(d, 8);
        float sc = d * 0.125f + logf(fmaxf(nw[e], 1e-10f));
        if ((lane & 15) == 0) scbuf[(size_t)j * 4 + h] = sc;
        mx = fmaxf(mx, sc);
    }

    float sum = 0.f;
    float4 macc = make_float4(0.f, 0.f, 0.f, 0.f);
    for (int j = beg; j < end; ++j) {
        int e = eids[j];
        int s = other[e];
        float sc = scbuf[(size_t)j * 4 + h];
        float ex = expf(sc - mx);
        sum += ex;
        float4 v = *(const float4*)(V + (size_t)s * 256 + lane * 4);
        macc.x += ex * v.x; macc.y += ex * v.y;
        macc.z += ex * v.z; macc.w += ex * v.w;
    }
    float inv = 1.f / (sum + 1e-10f);
    *(float4*)(msg + (size_t)t * 256 + lane * 4) =
        make_float4(macc.x * inv, macc.y * inv, macc.z * inv, macc.w * inv);
}

// ================= MFMA bf16x3 GEMM, latency-pipelined =================
// C[M,256] = act(concat(A1,A2)[M,K] @ W[K,256] + bias)
// Whi/Wlo: [256][K] bf16 (row n = column n of W).
// Block = 32 rows x 256 cols, 4 waves n-split (wave tile 32x64 = 2 subtiles 32x32).
// grid.x = ceil(M/32): I -> 1563 blocks (~6/CU, 24 waves/CU).
// All loads UNCONDITIONAL (row clamped to M-1; stores guarded) so the compiler can
// hoist them; explicit depth-2 register double-buffer on A and B keeps ~12-16
// loads in flight per wave. No LDS, no barriers.
// mfma_f32_32x32x16_bf16: A[l&31][(l>>5)*8+i], B[(l>>5)*8+i][l&31],
//                         C/D: col=l&31, row=(r&3)+8*(r>>2)+4*(l>>5).
template<int CONCAT>
__global__ __launch_bounds__(256) void gemm_mfma(
    const float* __restrict__ A1, const float* __restrict__ A2,
    const unsigned short* __restrict__ Whi, const unsigned short* __restrict__ Wlo,
    const float* __restrict__ bias, float* __restrict__ C, int M, int act)
{
    const int K = CONCAT ? 512 : 256;
    const int lane = threadIdx.x & 63;
    const int wv = threadIdx.x >> 6;       // 0..3 -> col block of 64
    const int bm = blockIdx.x * 32;
    const int lr = lane & 31;
    const int kg = (lane >> 5) << 3;       // 0 or 8

    const int arow = min(bm + lr, M - 1);  // clamp: loads unconditional
    const float* __restrict__ pa1 = A1 + (size_t)arow * 256;
    const float* __restrict__ pa2 = CONCAT ? (A2 + (size_t)arow * 256) : pa1;

    const int bc0 = wv * 64 + lr;
    const unsigned short* __restrict__ pb0h = Whi + (size_t)bc0 * K;
    const unsigned short* __restrict__ pb0l = Wlo + (size_t)bc0 * K;
    const unsigned short* __restrict__ pb1h = Whi + (size_t)(bc0 + 32) * K;
    const unsigned short* __restrict__ pb1l = Wlo + (size_t)(bc0 + 32) * K;

    f32x16 acc[2] = {};

    float4  a4[2][2];     // [buf][half] raw f32 A fragment
    ushort8 bq[2][4];     // [buf][b0h,b0l,b1h,b1l]

#define LOADA(B, k) do { \
        const float* _p = (CONCAT && (k) >= 256) ? (pa2 + ((k) - 256) + kg) \
                                                 : (pa1 + (k) + kg); \
        a4[B][0] = *(const float4*)_p; \
        a4[B][1] = *(const float4*)(_p + 4); \
    } while (0)

#define LOADB(B, k) do { \
        bq[B][0] = *(const ushort8*)(pb0h + (k) + kg); \
        bq[B][1] = *(const ushort8*)(pb0l + (k) + kg); \
        bq[B][2] = *(const ushort8*)(pb1h + (k) + kg); \
        bq[B][3] = *(const ushort8*)(pb1l + (k) + kg); \
    } while (0)

#define GSTEP(B, knext) do { \
        float xs[8] = {a4[B][0].x, a4[B][0].y, a4[B][0].z, a4[B][0].w, \
                       a4[B][1].x, a4[B][1].y, a4[B][1].z, a4[B][1].w}; \
        bf16x8 ah, al; \
        _Pragma("unroll") \
        for (int i = 0; i < 8; ++i) { \
            __bf16 h = (__bf16)xs[i]; \
            ah[i] = h; \
            al[i] = (__bf16)(xs[i] - (float)h); \
        } \
        LOADA(B, knext); \
        bf16x8 b0h = __builtin_bit_cast(bf16x8, bq[B][0]); \
        bf16x8 b0l = __builtin_bit_cast(bf16x8, bq[B][1]); \
        bf16x8 b1h = __builtin_bit_cast(bf16x8, bq[B][2]); \
        bf16x8 b1l = __builtin_bit_cast(bf16x8, bq[B][3]); \
        acc[0] = __builtin_amdgcn_mfma_f32_32x32x16_bf16(ah, b0h, acc[0], 0, 0, 0); \
        acc[0] = __builtin_amdgcn_mfma_f32_32x32x16_bf16(ah, b0l, acc[0], 0, 0, 0); \
        acc[0] = __builtin_amdgcn_mfma_f32_32x32x16_bf16(al, b0h, acc[0], 0, 0, 0); \
        acc[1] = __builtin_amdgcn_mfma_f32_32x32x16_bf16(ah, b1h, acc[1], 0, 0, 0); \
        acc[1] = __builtin_amdgcn_mfma_f32_32x32x16_bf16(ah, b1l, acc[1], 0, 0, 0); \
        acc[1] = __builtin_amdgcn_mfma_f32_32x32x16_bf16(al, b1h, acc[1], 0, 0, 0); \
        LOADB(B, knext); \
    } while (0)

    LOADA(0, 0);  LOADB(0, 0);
    LOADA(1, 16); LOADB(1, 16);

    for (int k0 = 0; k0 < K; k0 += 32) {
        int kn0 = (k0 + 32 < K) ? (k0 + 32) : k0;        // tail: harmless reload
        int kn1 = (k0 + 48 < K) ? (k0 + 48) : (k0 + 16);
        GSTEP(0, kn0);
        GSTEP(1, kn1);
    }
#undef LOADA
#undef LOADB
#undef GSTEP

    // ---- epilogue: bias + GELU + store ----
    #pragma unroll
    for (int nt = 0; nt < 2; ++nt) {
        int col = wv * 64 + nt * 32 + lr;
        float bv = bias ? bias[col] : 0.f;
        int rbase = bm + ((lane >> 5) << 2);
        #pragma unroll
        for (int r = 0; r < 16; ++r) {
            int row = rbase + (r & 3) + ((r >> 2) << 3);
            if (row < M) {
                float v = acc[nt][r] + bv;
                if (act) v = gelu_exact(v);
                C[(size_t)row * 256 + col] = v;
            }
        }
    }
}

// ================= host =================
extern "C" void kernel_launch(void* const* d_in, const int* in_sizes, int n_in,
                              void* d_out, int out_size, void* d_ws, size_t ws_size,
                              hipStream_t stream) {
    const float* inv_h    = (const float*)d_in[0];
    const float* asset_h  = (const float*)d_in[1];
    const float* inv_nw   = (const float*)d_in[2];
    const float* asset_nw = (const float*)d_in[3];
    const float* m_w1 = (const float*)d_in[4];
    const float* m_b1 = (const float*)d_in[5];
    const float* m_w2 = (const float*)d_in[6];
    const float* m_b2 = (const float*)d_in[7];
    const float* Wq   = (const float*)d_in[8];
    const float* Wk   = (const float*)d_in[9];
    const float* Wv   = (const float*)d_in[10];
    const float* u_w1 = (const float*)d_in[11];
    const float* u_b1 = (const float*)d_in[12];
    const float* u_w2 = (const float*)d_in[13];
    const float* u_b2 = (const float*)d_in[14];
    const int* etgt  = (const int*)d_in[15];
    const int* esrc  = (const int*)d_in[16];

    const int I = in_sizes[0] / 256;
    const int A = in_sizes[1] / 256;
    const int E = in_sizes[15];

    float* out_inv   = (float*)d_out;
    float* out_asset = (float*)d_out + (size_t)I * 256;

    char* wsp = (char*)d_ws;
    size_t off = 0;
    auto alloc = [&](size_t bytes) -> void* {
        void* p = wsp + off;
        off += (bytes + 255) & ~(size_t)255;
        return p;
    };
    float* X1 = (float*)alloc((size_t)I * 256 * 4);
    float* X2 = (float*)alloc((size_t)I * 256 * 4);
    float* Y1 = (float*)alloc((size_t)A * 256 * 4);
    float* Y2 = (float*)alloc((size_t)A * 256 * 4);
    float* msg_a = (float*)alloc((size_t)A * 256 * 4);
    float* scbuf = (float*)alloc((size_t)E * 4 * 4);
    int* cnt_i  = (int*)alloc((size_t)I * 4);
    int* cnt_a  = (int*)alloc((size_t)A * 4);
    int* offs_i = (int*)alloc((size_t)(I + 1) * 4);
    int* offs_a = (int*)alloc((size_t)(A + 1) * 4);
    int* eid_i  = (int*)alloc((size_t)E * 4);
    int* eid_a  = (int*)alloc((size_t)E * 4);
    int* bsum_i = (int*)alloc(256 * 4);
    int* bsum_a = (int*)alloc(256 * 4);
    float* msg_i = X2;   // overlays X2 (K_i dead before msg_i written)

    // pre-split weights (hi/lo bf16, transposed [N=256][K])
    PrepArgs pa;
    const float* wsrc[7] = {m_w1, m_w2, Wq, Wk, Wv, u_w1, u_w2};
    const int    wK[7]   = {256, 256, 256, 256, 256, 512, 256};
    unsigned short* whi[7];
    unsigned short* wlo[7];
    pa.off[0] = 0;
    for (int i = 0; i < 7; ++i) {
        whi[i] = (unsigned short*)alloc((size_t)wK[i] * 256 * 2);
        wlo[i] = (unsigned short*)alloc((size_t)wK[i] * 256 * 2);
        pa.src[i] = wsrc[i];
        pa.hi[i] = whi[i];
        pa.lo[i] = wlo[i];
        pa.K[i] = wK[i];
        pa.off[i + 1] = pa.off[i] + wK[i];
    }

    const int nbI = (I + 255) / 256;
    const int nbA = (A + 255) / 256;
    const int nbE = (E + 255) / 256;

    // ---- weight prep (independent of CSR) ----
    hipLaunchKernelGGL(prep_all, dim3(pa.off[7]), dim3(256), 0, stream, pa);

    // ---- CSR build (both directions) ----
    hipMemsetAsync(cnt_i, 0, ((size_t)I + A) * 4 + 256 - 256, stream);
    hipMemsetAsync(cnt_a, 0, (size_t)A * 4, stream);
    hipLaunchKernelGGL(count_kernel, dim3(nbE), dim3(256), 0, stream,
                       etgt, esrc, cnt_i, cnt_a, E);
    hipLaunchKernelGGL(scan_block, dim3(nbI), dim3(256), 0, stream, cnt_i, offs_i, bsum_i, I);
    hipLaunchKernelGGL(scan_block, dim3(nbA), dim3(256), 0, stream, cnt_a, offs_a, bsum_a, A);
    hipLaunchKernelGGL(scan_bsum, dim3(1), dim3(256), 0, stream, bsum_i, nbI);
    hipLaunchKernelGGL(scan_bsum, dim3(1), dim3(256), 0, stream, bsum_a, nbA);
    hipLaunchKernelGGL(add_offs, dim3(nbI), dim3(256), 0, stream, offs_i, cnt_i, bsum_i, I, E);
    hipLaunchKernelGGL(add_offs, dim3(nbA), dim3(256), 0, stream, offs_a, cnt_a, bsum_a, A, E);
    hipLaunchKernelGGL(fill_kernel, dim3(nbE), dim3(256), 0, stream,
                       etgt, esrc, cnt_i, cnt_a, eid_i, eid_a, E);

    auto gemm = [&](const float* A1p, const float* A2p, int M, int widx,
                    const float* bias, float* Cm, int act, int concat) {
        dim3 grid((M + 31) / 32);
        if (concat) hipLaunchKernelGGL((gemm_mfma<1>), grid, dim3(256), 0, stream,
                                       A1p, A2p, whi[widx], wlo[widx], bias, Cm, M, act);
        else        hipLaunchKernelGGL((gemm_mfma<0>), grid, dim3(256), 0, stream,
                                       A1p, A2p, whi[widx], wlo[widx], bias, Cm, M, act);
    };
    // widx: 0=m_w1 1=m_w2 2=Wq 3=Wk 4=Wv 5=u_w1 6=u_w2

    // ===== direction 2: assets aggregate from investors (segments = esrc) =====
    gemm(inv_h, nullptr, I, 0, m_b1, X1, 1, 0);     // t_i
    gemm(X1,    nullptr, I, 1, m_b2, X2, 1, 0);     // M_i
    gemm(X2,    nullptr, I, 4, nullptr, X1, 0, 0);  // V_i
    gemm(inv_h, nullptr, I, 3, nullptr, X2, 0, 0);  // K_i
    gemm(asset_h, nullptr, A, 2, nullptr, Y1, 0, 0);// Q_a

    hipLaunchKernelGGL(fused_attn, dim3((A + 3) / 4), dim3(256), 0, stream,
                       Y1, X2, X1, offs_a, eid_a, etgt, asset_nw, scbuf, msg_a, A);

    gemm(asset_h, msg_a, A, 5, u_b1, Y2, 1, 1);     // hid_a
    gemm(Y2, nullptr, A, 6, u_b2, out_asset, 1, 0);

    // ===== direction 1: investors aggregate from assets (segments = etgt) =====
    gemm(asset_h, nullptr, A, 0, m_b1, Y1, 1, 0);   // t_a
    gemm(Y1,      nullptr, A, 1, m_b2, Y2, 1, 0);   // M_a
    gemm(Y2,      nullptr, A, 4, nullptr, Y1, 0, 0);// V_a
    gemm(asset_h, nullptr, A, 3, nullptr, Y2, 0, 0);// K_a
    gemm(inv_h,   nullptr, I, 2, nullptr, X1, 0, 0);// Q_i

    hipLaunchKernelGGL(fused_attn, dim3((I + 3) / 4), dim3(256), 0, stream,
                       X1, Y2, Y1, offs_i, eid_i, esrc, inv_nw, scbuf, msg_i, I);

    gemm(inv_h, msg_i, I, 5, u_b1, X1, 1, 1);       // hid_i
    gemm(X1, nullptr, I, 6, u_b2, out_inv, 1, 0);
}

// Round 3
// 1163.536 us; speedup vs baseline: 1.1321x; 1.1321x over previous
//
#include <hip/hip_runtime.h>

typedef __bf16 bf16x8 __attribute__((ext_vector_type(8)));
typedef float f32x16 __attribute__((ext_vector_type(16)));
typedef unsigned short ushort8 __attribute__((ext_vector_type(8)));

// ---------- helpers ----------
__device__ __forceinline__ float gelu_exact(float x) {
    return 0.5f * x * (1.0f + erff(x * 0.70710678118654752440f));
}

// =====================================================================
// Packed operand layout (bf16 hi/lo, MFMA-fragment-linear):
//   A-pack for [M][256]: slot s = (rb*16 + kb)*64 + lane, 8 ushorts each.
//     lane's elems = A[rb*32 + (lane&31)][kb*16 + (lane>>5)*8 + i], i=0..7
//   B-pack for W[K][256]: slot = (nb*KB + kb)*64 + lane, KB = K/16.
//     lane's elems = W[kb*16 + (lane>>5)*8 + i][nb*32 + (lane&31)]
//   These are exactly the v_mfma_f32_32x32x16_bf16 A/B fragments, so the
//   GEMM hot loop is pure coalesced 16B streaming loads + MFMA.
// =====================================================================

// ================= CSR build =================
__global__ __launch_bounds__(256) void count_kernel(
    const int* __restrict__ tgt, const int* __restrict__ src,
    int* __restrict__ cnt_i, int* __restrict__ cnt_a, int E)
{
    int e = blockIdx.x * 256 + threadIdx.x;
    if (e < E) {
        atomicAdd(&cnt_i[tgt[e]], 1);
        atomicAdd(&cnt_a[src[e]], 1);
    }
}

__global__ __launch_bounds__(256) void scan_block(
    const int* __restrict__ cnt, int* __restrict__ offs, int* __restrict__ bsum, int N)
{
    __shared__ int s[256];
    int i = blockIdx.x * 256 + threadIdx.x;
    int v = (i < N) ? cnt[i] : 0;
    s[threadIdx.x] = v;
    __syncthreads();
    for (int d = 1; d < 256; d <<= 1) {
        int t = (threadIdx.x >= d) ? s[threadIdx.x - d] : 0;
        __syncthreads();
        s[threadIdx.x] += t;
        __syncthreads();
    }
    if (i < N) offs[i] = s[threadIdx.x] - v;   // exclusive
    if (threadIdx.x == 255) bsum[blockIdx.x] = s[255];
}

__global__ __launch_bounds__(256) void scan_bsum(int* __restrict__ bsum, int nb)
{
    __shared__ int s[256];
    int v = (threadIdx.x < nb) ? bsum[threadIdx.x] : 0;
    s[threadIdx.x] = v;
    __syncthreads();
    for (int d = 1; d < 256; d <<= 1) {
        int t = (threadIdx.x >= d) ? s[threadIdx.x - d] : 0;
        __syncthreads();
        s[threadIdx.x] += t;
        __syncthreads();
    }
    if (threadIdx.x < nb) bsum[threadIdx.x] = s[threadIdx.x] - v;  // exclusive
}

__global__ __launch_bounds__(256) void add_offs(
    int* __restrict__ offs, int* __restrict__ cursor,
    const int* __restrict__ bsum, int N, int E)
{
    int i = blockIdx.x * 256 + threadIdx.x;
    if (i < N) {
        int f = offs[i] + bsum[blockIdx.x];
        offs[i] = f;
        cursor[i] = f;
    }
    if (i == 0) offs[N] = E;
}

__global__ __launch_bounds__(256) void fill_kernel(
    const int* __restrict__ tgt, const int* __restrict__ src,
    int* __restrict__ cur_i, int* __restrict__ cur_a,
    int* __restrict__ eid_i, int* __restrict__ eid_a, int E)
{
    int e = blockIdx.x * 256 + threadIdx.x;
    if (e < E) {
        int p = atomicAdd(&cur_i[tgt[e]], 1);
        eid_i[p] = e;
        int q = atomicAdd(&cur_a[src[e]], 1);
        eid_a[q] = e;
    }
}

// ================= weight prep: f32 W[K][256] -> packed B fragments =================
struct PrepArgs {
    const float* src[7];
    unsigned short* hi[7];
    unsigned short* lo[7];
    int K[7];
    int off[8];   // slot offsets; slots per matrix = (K/16)*8*64
};

__global__ __launch_bounds__(256) void prep_w(PrepArgs a)
{
    int s = blockIdx.x * 256 + threadIdx.x;
    if (s >= a.off[7]) return;
    int m = 0;
    #pragma unroll
    for (int i = 0; i < 6; ++i) m += (s >= a.off[i + 1]) ? 1 : 0;
    int sl = s - a.off[m];
    int KB = a.K[m] >> 4;
    int l  = sl & 63;
    int kb = (sl >> 6) % KB;
    int nb = (sl >> 6) / KB;
    int n  = nb * 32 + (l & 31);
    int k0 = kb * 16 + ((l >> 5) << 3);
    ushort8 hh, ll;
    #pragma unroll
    for (int i = 0; i < 8; ++i) {
        float x = a.src[m][(size_t)(k0 + i) * 256 + n];
        __bf16 h = (__bf16)x;
        hh[i] = __builtin_bit_cast(unsigned short, h);
        ll[i] = __builtin_bit_cast(unsigned short, (__bf16)(x - (float)h));
    }
    *(ushort8*)(a.hi[m] + (size_t)sl * 8) = hh;
    *(ushort8*)(a.lo[m] + (size_t)sl * 8) = ll;
}

// ================= row pack: f32 X[M][256] -> packed A fragments =================
__global__ __launch_bounds__(256) void pack_rows(
    const float* __restrict__ X, unsigned short* __restrict__ Ph,
    unsigned short* __restrict__ Pl, int M, int RB)
{
    int s = blockIdx.x * 256 + threadIdx.x;
    int total = RB * 16 * 64;
    if (s >= total) return;
    int l  = s & 63;
    int kb = (s >> 6) & 15;
    int rb = s >> 10;
    int row = min(rb * 32 + (l & 31), M - 1);
    int k0  = kb * 16 + ((l >> 5) << 3);
    const float* p = X + (size_t)row * 256 + k0;
    float4 f0 = *(const float4*)p;
    float4 f1 = *(const float4*)(p + 4);
    float xs[8] = {f0.x, f0.y, f0.z, f0.w, f1.x, f1.y, f1.z, f1.w};
    ushort8 hh, ll;
    #pragma unroll
    for (int i = 0; i < 8; ++i) {
        __bf16 h = (__bf16)xs[i];
        hh[i] = __builtin_bit_cast(unsigned short, h);
        ll[i] = __builtin_bit_cast(unsigned short, (__bf16)(xs[i] - (float)h));
    }
    *(ushort8*)(Ph + (size_t)s * 8) = hh;
    *(ushort8*)(Pl + (size_t)s * 8) = ll;
}

// ================= fused per-target attention =================
// Unchanged math; msg is now written directly in packed A-fragment hi/lo form
// (identical numerics to the f32->hi/lo split previously done inside the GEMM).
__global__ __launch_bounds__(256) void fused_attn(
    const float* __restrict__ Q, const float* __restrict__ Kk, const float* __restrict__ V,
    const int* __restrict__ offs, const int* __restrict__ eids,
    const int* __restrict__ other, const float* __restrict__ nw,
    float* __restrict__ scbuf, unsigned short* __restrict__ msgH,
    unsigned short* __restrict__ msgL, int T)
{
    int w = blockIdx.x * 4 + (threadIdx.x >> 6);
    int lane = threadIdx.x & 63;
    if (w >= T) return;
    int t = w;
    int beg = offs[t], end = offs[t + 1];
    int h = lane >> 4;

    float4 q = *(const float4*)(Q + (size_t)t * 256 + lane * 4);

    float mx = 0.f;
    for (int j = beg; j < end; ++j) {
        int e = eids[j];
        int s = other[e];
        float4 k = *(const float4*)(Kk + (size_t)s * 256 + lane * 4);
        float d = q.x * k.x + q.y * k.y + q.z * k.z + q.w * k.w;
        d += __shfl_xor(d, 1);
        d += __shfl_xor(d, 2);
        d += __shfl_xor(d, 4);
        d += __shfl_xor(d, 8);
        float sc = d * 0.125f + logf(fmaxf(nw[e], 1e-10f));
        if ((lane & 15) == 0) scbuf[(size_t)j * 4 + h] = sc;
        mx = fmaxf(mx, sc);
    }

    float sum = 0.f;
    float4 macc = make_float4(0.f, 0.f, 0.f, 0.f);
    for (int j = beg; j < end; ++j) {
        int e = eids[j];
        int s = other[e];
        float sc = scbuf[(size_t)j * 4 + h];
        float ex = expf(sc - mx);
        sum += ex;
        float4 v = *(const float4*)(V + (size_t)s * 256 + lane * 4);
        macc.x += ex * v.x; macc.y += ex * v.y;
        macc.z += ex * v.z; macc.w += ex * v.w;
    }
    float inv = 1.f / (sum + 1e-10f);
    float vals[4] = {macc.x * inv, macc.y * inv, macc.z * inv, macc.w * inv};
    unsigned short hs[4], ls[4];
    #pragma unroll
    for (int i = 0; i < 4; ++i) {
        __bf16 hh = (__bf16)vals[i];
        hs[i] = __builtin_bit_cast(unsigned short, hh);
        ls[i] = __builtin_bit_cast(unsigned short, (__bf16)(vals[i] - (float)hh));
    }
    // packed slot: cols c = 4*lane..4*lane+3 of row t
    size_t base = (((size_t)(t >> 5) * 16 + (lane >> 2)) * 64 + ((lane >> 1) & 1) * 32 + (t & 31)) * 8
                + ((lane & 1) << 2);
    *(ushort4*)(msgH + base) = make_ushort4(hs[0], hs[1], hs[2], hs[3]);
    *(ushort4*)(msgL + base) = make_ushort4(ls[0], ls[1], ls[2], ls[3]);
}

// ================= packed-operand MFMA bf16x3 GEMM =================
// C = act(A @ W + bias), A: M x (CONCAT?512:256) given as packed fragments,
// W: packed fragments. Block = 128 rows x 128 cols (grid.y=2), 4 waves 2x2,
// wave = 64x64 = 2x2 subtiles of 32x32. Hot loop: 8 coalesced 16B loads +
// 12 MFMA per 16-k, depth-2 double buffer, no LDS, no barriers.
// Epilogue: per-wave LDS transpose (pad 33, conflict-free), then either
// float4 f32 stores (PACKOUT=0) or packed hi/lo fragment stores (PACKOUT=1).
template<int CONCAT, int PACKOUT>
__global__ __launch_bounds__(256) void gemm_pk(
    const unsigned short* __restrict__ Ah, const unsigned short* __restrict__ Al,
    const unsigned short* __restrict__ A2h, const unsigned short* __restrict__ A2l,
    const unsigned short* __restrict__ Bh, const unsigned short* __restrict__ Bl,
    const float* __restrict__ bias, int act, int M,
    float* __restrict__ Cf, unsigned short* __restrict__ Ch, unsigned short* __restrict__ Cl)
{
    const int KB = CONCAT ? 32 : 16;     // B k-blocks
    const int RB = (M + 31) >> 5;
    const int lane = threadIdx.x & 63;
    const int w = threadIdx.x >> 6;
    const int wm = w >> 1, wn = w & 1;

    const int rb0 = blockIdx.x * 4 + wm * 2;
    const int rbl0 = min(rb0, RB - 1);
    const int rbl1 = min(rb0 + 1, RB - 1);
    const int nb0 = blockIdx.y * 4 + wn * 2;

    f32x16 acc[2][2] = {};

    struct KFrag { ushort8 a0h, a0l, a1h, a1l, b0h, b0l, b1h, b1l; };

    auto loadf = [&](KFrag& F, int kb) {
        const unsigned short *ph, *pl;
        int kba;
        if (CONCAT && kb >= 16) { ph = A2h; pl = A2l; kba = kb - 16; }
        else                    { ph = Ah;  pl = Al;  kba = kb; }
        size_t s0 = ((size_t)(rbl0 * 16 + kba) * 64 + lane) * 8;
        size_t s1 = ((size_t)(rbl1 * 16 + kba) * 64 + lane) * 8;
        F.a0h = *(const ushort8*)(ph + s0);
        F.a0l = *(const ushort8*)(pl + s0);
        F.a1h = *(const ushort8*)(ph + s1);
        F.a1l = *(const ushort8*)(pl + s1);
        size_t t0 = ((size_t)((nb0 + 0) * KB + kb) * 64 + lane) * 8;
        size_t t1 = ((size_t)((nb0 + 1) * KB + kb) * 64 + lane) * 8;
        F.b0h = *(const ushort8*)(Bh + t0);
        F.b0l = *(const ushort8*)(Bl + t0);
        F.b1h = *(const ushort8*)(Bh + t1);
        F.b1l = *(const ushort8*)(Bl + t1);
    };

    auto compf = [&](const KFrag& F) {
        bf16x8 a0h = __builtin_bit_cast(bf16x8, F.a0h);
        bf16x8 a0l = __builtin_bit_cast(bf16x8, F.a0l);
        bf16x8 a1h = __builtin_bit_cast(bf16x8, F.a1h);
        bf16x8 a1l = __builtin_bit_cast(bf16x8, F.a1l);
        bf16x8 b0h = __builtin_bit_cast(bf16x8, F.b0h);
        bf16x8 b0l = __builtin_bit_cast(bf16x8, F.b0l);
        bf16x8 b1h = __builtin_bit_cast(bf16x8, F.b1h);
        bf16x8 b1l = __builtin_bit_cast(bf16x8, F.b1l);
        acc[0][0] = __builtin_amdgcn_mfma_f32_32x32x16_bf16(a0h, b0h, acc[0][0], 0, 0, 0);
        acc[0][0] = __builtin_amdgcn_mfma_f32_32x32x16_bf16(a0h, b0l, acc[0][0], 0, 0, 0);
        acc[0][0] = __builtin_amdgcn_mfma_f32_32x32x16_bf16(a0l, b0h, acc[0][0], 0, 0, 0);
        acc[0][1] = __builtin_amdgcn_mfma_f32_32x32x16_bf16(a0h, b1h, acc[0][1], 0, 0, 0);
        acc[0][1] = __builtin_amdgcn_mfma_f32_32x32x16_bf16(a0h, b1l, acc[0][1], 0, 0, 0);
        acc[0][1] = __builtin_amdgcn_mfma_f32_32x32x16_bf16(a0l, b1h, acc[0][1], 0, 0, 0);
        acc[1][0] = __builtin_amdgcn_mfma_f32_32x32x16_bf16(a1h, b0h, acc[1][0], 0, 0, 0);
        acc[1][0] = __builtin_amdgcn_mfma_f32_32x32x16_bf16(a1h, b0l, acc[1][0], 0, 0, 0);
        acc[1][0] = __builtin_amdgcn_mfma_f32_32x32x16_bf16(a1l, b0h, acc[1][0], 0, 0, 0);
        acc[1][1] = __builtin_amdgcn_mfma_f32_32x32x16_bf16(a1h, b1h, acc[1][1], 0, 0, 0);
        acc[1][1] = __builtin_amdgcn_mfma_f32_32x32x16_bf16(a1h, b1l, acc[1][1], 0, 0, 0);
        acc[1][1] = __builtin_amdgcn_mfma_f32_32x32x16_bf16(a1l, b1h, acc[1][1], 0, 0, 0);
    };

    KFrag F0, F1;
    loadf(F0, 0);
    loadf(F1, 1);
    const int KT = CONCAT ? 32 : 16;
    for (int kb = 0; kb < KT; kb += 2) {
        compf(F0);
        if (kb + 2 < KT) loadf(F0, kb + 2);
        compf(F1);
        if (kb + 3 < KT) loadf(F1, kb + 3);
    }

    // ---- epilogue: bias + act, per-wave LDS transpose, coalesced stores ----
    __shared__ float tbuf[4][32 * 33];
    const int m2 = lane & 31;

    #pragma unroll
    for (int mt = 0; mt < 2; ++mt) {
        int rb = rb0 + mt;
        bool rvalid = rb < RB;
        int mg = rb * 32 + m2;
        #pragma unroll
        for (int nt = 0; nt < 2; ++nt) {
            int nb = nb0 + nt;
            float bv = bias ? bias[nb * 32 + (lane & 31)] : 0.f;
            #pragma unroll
            for (int r = 0; r < 16; ++r) {
                int ml = (r & 3) + ((r >> 2) << 3) + ((lane >> 5) << 2);
                float v = acc[mt][nt][r] + bv;
                if (act) v = gelu_exact(v);
                tbuf[w][ml * 33 + (lane & 31)] = v;
            }
            asm volatile("s_waitcnt lgkmcnt(0)" ::: "memory");
            #pragma unroll
            for (int qq = 0; qq < 2; ++qq) {
                int c0 = ((lane >> 5) << 3) + (qq << 4);   // 0,8,16,24 local col
                float vs[8];
                #pragma unroll
                for (int i = 0; i < 8; ++i) vs[i] = tbuf[w][m2 * 33 + c0 + i];
                if (PACKOUT) {
                    ushort8 hh, ll;
                    #pragma unroll
                    for (int i = 0; i < 8; ++i) {
                        __bf16 hb = (__bf16)vs[i];
                        hh[i] = __builtin_bit_cast(unsigned short, hb);
                        ll[i] = __builtin_bit_cast(unsigned short, (__bf16)(vs[i] - (float)hb));
                    }
                    int ng = nb * 32 + c0;
                    size_t slot = (((size_t)rb * 16 + (ng >> 4)) * 64 + ((ng >> 3) & 1) * 32 + m2) * 8;
                    if (rvalid) {
                        *(ushort8*)(Ch + slot) = hh;
                        *(ushort8*)(Cl + slot) = ll;
                    }
                } else {
                    if (mg < M) {
                        float* cp = Cf + (size_t)mg * 256 + nb * 32 + c0;
                        *(float4*)(cp)     = make_float4(vs[0], vs[1], vs[2], vs[3]);
                        *(float4*)(cp + 4) = make_float4(vs[4], vs[5], vs[6], vs[7]);
                    }
                }
            }
            asm volatile("s_waitcnt lgkmcnt(0)" ::: "memory");  // tbuf reuse safe (same wave)
        }
    }
}

// ================= host =================
extern "C" void kernel_launch(void* const* d_in, const int* in_sizes, int n_in,
                              void* d_out, int out_size, void* d_ws, size_t ws_size,
                              hipStream_t stream) {
    const float* inv_h    = (const float*)d_in[0];
    const float* asset_h  = (const float*)d_in[1];
    const float* inv_nw   = (const float*)d_in[2];
    const float* asset_nw = (const float*)d_in[3];
    const float* m_w1 = (const float*)d_in[4];
    const float* m_b1 = (const float*)d_in[5];
    const float* m_w2 = (const float*)d_in[6];
    const float* m_b2 = (const float*)d_in[7];
    const float* Wq   = (const float*)d_in[8];
    const float* Wk   = (const float*)d_in[9];
    const float* Wv   = (const float*)d_in[10];
    const float* u_w1 = (const float*)d_in[11];
    const float* u_b1 = (const float*)d_in[12];
    const float* u_w2 = (const float*)d_in[13];
    const float* u_b2 = (const float*)d_in[14];
    const int* etgt  = (const int*)d_in[15];
    const int* esrc  = (const int*)d_in[16];

    const int I = in_sizes[0] / 256;
    const int A = in_sizes[1] / 256;
    const int E = in_sizes[15];
    const int RBI = (I + 31) >> 5;
    const int RBA = (A + 31) >> 5;

    float* out_inv   = (float*)d_out;
    float* out_asset = (float*)d_out + (size_t)I * 256;

    char* wsp = (char*)d_ws;
    size_t off = 0;
    auto alloc = [&](size_t bytes) -> char* {
        char* p = wsp + off;
        off += (bytes + 255) & ~(size_t)255;
        return p;
    };

    const size_t ipackHalf = (size_t)RBI * 16384;  // bytes per half (hi or lo)
    const size_t apackHalf = (size_t)RBA * 16384;
    const size_t if32 = (size_t)I * 1024;
    const size_t af32 = (size_t)A * 1024;
    const size_t r_sz = (2 * ipackHalf > if32) ? 2 * ipackHalf : if32;
    const size_t s_sz = (2 * apackHalf > af32) ? 2 * apackHalf : af32;

    unsigned short* invP_h  = (unsigned short*)alloc(ipackHalf);
    unsigned short* invP_l  = (unsigned short*)alloc(ipackHalf);
    unsigned short* astP_h  = (unsigned short*)alloc(apackHalf);
    unsigned short* astP_l  = (unsigned short*)alloc(apackHalf);
    char* R1 = alloc(r_sz);   // tP_i pack | V_i f32 | Q_i f32 | hidP_i pack
    char* R2 = alloc(r_sz);   // MP_i pack | K_i f32 | msgP_i pack
    char* S1 = alloc(s_sz);   // Q_a f32 | tP_a pack | V_a f32
    char* S2 = alloc(s_sz);   // msgP_a pack | MP_a pack | K_a f32
    char* S3 = alloc(s_sz);   // hidP_a pack
    float* scbuf = (float*)alloc((size_t)E * 4 * 4);
    int* cnt_i  = (int*)alloc((size_t)I * 4);
    int* cnt_a  = (int*)alloc((size_t)A * 4);
    int* offs_i = (int*)alloc((size_t)(I + 1) * 4);
    int* offs_a = (int*)alloc((size_t)(A + 1) * 4);
    int* eid_i  = (int*)alloc((size_t)E * 4);
    int* eid_a  = (int*)alloc((size_t)E * 4);
    int* bsum_i = (int*)alloc(256 * 4);
    int* bsum_a = (int*)alloc(256 * 4);

    // weight packs
    PrepArgs pa;
    const float* wsrc[7] = {m_w1, m_w2, Wq, Wk, Wv, u_w1, u_w2};
    const int    wK[7]   = {256, 256, 256, 256, 256, 512, 256};
    unsigned short* wph[7];
    unsigned short* wpl[7];
    pa.off[0] = 0;
    for (int i = 0; i < 7; ++i) {
        size_t slots = (size_t)(wK[i] >> 4) * 8 * 64;
        wph[i] = (unsigned short*)alloc(slots * 16);
        wpl[i] = (unsigned short*)alloc(slots * 16);
        pa.src[i] = wsrc[i];
        pa.hi[i] = wph[i];
        pa.lo[i] = wpl[i];
        pa.K[i] = wK[i];
        pa.off[i + 1] = pa.off[i] + (int)slots;
    }

    const int nbI = (I + 255) / 256;
    const int nbA = (A + 255) / 256;
    const int nbE = (E + 255) / 256;

    // ---- operand prep ----
    hipLaunchKernelGGL(prep_w, dim3((pa.off[7] + 255) / 256), dim3(256), 0, stream, pa);
    hipLaunchKernelGGL(pack_rows, dim3((RBI * 1024 + 255) / 256), dim3(256), 0, stream,
                       inv_h, invP_h, invP_l, I, RBI);
    hipLaunchKernelGGL(pack_rows, dim3((RBA * 1024 + 255) / 256), dim3(256), 0, stream,
                       asset_h, astP_h, astP_l, A, RBA);

    // ---- CSR build ----
    hipMemsetAsync(cnt_i, 0, (size_t)I * 4, stream);
    hipMemsetAsync(cnt_a, 0, (size_t)A * 4, stream);
    hipLaunchKernelGGL(count_kernel, dim3(nbE), dim3(256), 0, stream,
                       etgt, esrc, cnt_i, cnt_a, E);
    hipLaunchKernelGGL(scan_block, dim3(nbI), dim3(256), 0, stream, cnt_i, offs_i, bsum_i, I);
    hipLaunchKernelGGL(scan_block, dim3(nbA), dim3(256), 0, stream, cnt_a, offs_a, bsum_a, A);
    hipLaunchKernelGGL(scan_bsum, dim3(1), dim3(256), 0, stream, bsum_i, nbI);
    hipLaunchKernelGGL(scan_bsum, dim3(1), dim3(256), 0, stream, bsum_a, nbA);
    hipLaunchKernelGGL(add_offs, dim3(nbI), dim3(256), 0, stream, offs_i, cnt_i, bsum_i, I, E);
    hipLaunchKernelGGL(add_offs, dim3(nbA), dim3(256), 0, stream, offs_a, cnt_a, bsum_a, A, E);
    hipLaunchKernelGGL(fill_kernel, dim3(nbE), dim3(256), 0, stream,
                       etgt, esrc, cnt_i, cnt_a, eid_i, eid_a, E);

    // gemm launcher. outmode: 0 = f32 Cf, 1 = packed (cH,cL)
    auto gemm = [&](const unsigned short* aH, const unsigned short* aL,
                    const unsigned short* a2H, const unsigned short* a2L,
                    int M, int widx, const float* bias, int act,
                    float* cf, unsigned short* cH, unsigned short* cL, int concat) {
        dim3 grid((M + 127) / 128, 2);
        if (concat) {
            if (cf) hipLaunchKernelGGL((gemm_pk<1,0>), grid, dim3(256), 0, stream,
                        aH, aL, a2H, a2L, wph[widx], wpl[widx], bias, act, M, cf, cH, cL);
            else    hipLaunchKernelGGL((gemm_pk<1,1>), grid, dim3(256), 0, stream,
                        aH, aL, a2H, a2L, wph[widx], wpl[widx], bias, act, M, cf, cH, cL);
        } else {
            if (cf) hipLaunchKernelGGL((gemm_pk<0,0>), grid, dim3(256), 0, stream,
                        aH, aL, a2H, a2L, wph[widx], wpl[widx], bias, act, M, cf, cH, cL);
            else    hipLaunchKernelGGL((gemm_pk<0,1>), grid, dim3(256), 0, stream,
                        aH, aL, a2H, a2L, wph[widx], wpl[widx], bias, act, M, cf, cH, cL);
        }
    };
    // widx: 0=m_w1 1=m_w2 2=Wq 3=Wk 4=Wv 5=u_w1 6=u_w2

    auto ph = [&](char* r) { return (unsigned short*)r; };
    auto plI = [&](char* r) { return (unsigned short*)(r + ipackHalf); };
    auto plA = [&](char* r) { return (unsigned short*)(r + apackHalf); };

    // ===== direction 2: assets aggregate from investors =====
    gemm(invP_h, invP_l, 0, 0, I, 0, m_b1, 1, nullptr, ph(R1), plI(R1), 0);   // tP_i -> R1
    gemm(ph(R1), plI(R1), 0, 0, I, 1, m_b2, 1, nullptr, ph(R2), plI(R2), 0);  // MP_i -> R2
    gemm(ph(R2), plI(R2), 0, 0, I, 4, nullptr, 0, (float*)R1, 0, 0, 0);       // V_i f32 -> R1
    gemm(invP_h, invP_l, 0, 0, I, 3, nullptr, 0, (float*)R2, 0, 0, 0);        // K_i f32 -> R2
    gemm(astP_h, astP_l, 0, 0, A, 2, nullptr, 0, (float*)S1, 0, 0, 0);        // Q_a f32 -> S1

    hipLaunchKernelGGL(fused_attn, dim3((A + 3) / 4), dim3(256), 0, stream,
                       (float*)S1, (float*)R2, (float*)R1, offs_a, eid_a, etgt, asset_nw,
                       scbuf, ph(S2), plA(S2), A);                            // msgP_a -> S2

    gemm(astP_h, astP_l, ph(S2), plA(S2), A, 5, u_b1, 1, nullptr, ph(S3), plA(S3), 1); // hidP_a -> S3
    gemm(ph(S3), plA(S3), 0, 0, A, 6, u_b2, 1, out_asset, 0, 0, 0);

    // ===== direction 1: investors aggregate from assets =====
    gemm(astP_h, astP_l, 0, 0, A, 0, m_b1, 1, nullptr, ph(S1), plA(S1), 0);   // tP_a -> S1
    gemm(ph(S1), plA(S1), 0, 0, A, 1, m_b2, 1, nullptr, ph(S2), plA(S2), 0);  // MP_a -> S2
    gemm(ph(S2), plA(S2), 0, 0, A, 4, nullptr, 0, (float*)S1, 0, 0, 0);       // V_a f32 -> S1
    gemm(astP_h, astP_l, 0, 0, A, 3, nullptr, 0, (float*)S2, 0, 0, 0);        // K_a f32 -> S2
    gemm(invP_h, invP_l, 0, 0, I, 2, nullptr, 0, (float*)R1, 0, 0, 0);        // Q_i f32 -> R1

    hipLaunchKernelGGL(fused_attn, dim3((I + 3) / 4), dim3(256), 0, stream,
                       (float*)R1, (float*)S2, (float*)S1, offs_i, eid_i, esrc, inv_nw,
                       scbuf, ph(R2), plI(R2), I);                            // msgP_i -> R2

    gemm(invP_h, invP_l, ph(R2), plI(R2), I, 5, u_b1, 1, nullptr, ph(R1), plI(R1), 1); // hidP_i -> R1
    gemm(ph(R1), plI(R1), 0, 0, I, 6, u_b2, 1, out_inv, 0, 0, 0);
}

// Round 4
// 1105.135 us; speedup vs baseline: 1.1920x; 1.0528x over previous
//
#include <hip/hip_runtime.h>

typedef __bf16 bf16x8 __attribute__((ext_vector_type(8)));
typedef float f32x16 __attribute__((ext_vector_type(16)));
typedef unsigned short ushort8 __attribute__((ext_vector_type(8)));

// ---------- helpers ----------
__device__ __forceinline__ float gelu_exact(float x) {
    return 0.5f * x * (1.0f + erff(x * 0.70710678118654752440f));
}

// async global->LDS, 16B per lane; dest is wave-uniform base, HW adds lane*16
__device__ __forceinline__ void gload_lds16(const void* g, void* l) {
    __builtin_amdgcn_global_load_lds(
        (const __attribute__((address_space(1))) unsigned int*)g,
        (__attribute__((address_space(3))) unsigned int*)l, 16, 0, 0);
}

// =====================================================================
// Packed operand layout (bf16 hi/lo, MFMA-fragment-linear):
//   A-pack for [M][256]: slot s = (rb*16 + kb)*64 + lane, 8 ushorts each.
//     lane's elems = A[rb*32 + (lane&31)][kb*16 + (lane>>5)*8 + i], i=0..7
//   B-pack for W[K][256]: slot = (nb*KB + kb)*64 + lane, KB = K/16.
//     lane's elems = W[kb*16 + (lane>>5)*8 + i][nb*32 + (lane&31)]
//   One fragment = 1 KB contiguous per wave -> exactly one global_load_lds.
// =====================================================================

// ================= CSR build =================
__global__ __launch_bounds__(256) void count_kernel(
    const int* __restrict__ tgt, const int* __restrict__ src,
    int* __restrict__ cnt_i, int* __restrict__ cnt_a, int E)
{
    int e = blockIdx.x * 256 + threadIdx.x;
    if (e < E) {
        atomicAdd(&cnt_i[tgt[e]], 1);
        atomicAdd(&cnt_a[src[e]], 1);
    }
}

__global__ __launch_bounds__(256) void scan_block(
    const int* __restrict__ cnt, int* __restrict__ offs, int* __restrict__ bsum, int N)
{
    __shared__ int s[256];
    int i = blockIdx.x * 256 + threadIdx.x;
    int v = (i < N) ? cnt[i] : 0;
    s[threadIdx.x] = v;
    __syncthreads();
    for (int d = 1; d < 256; d <<= 1) {
        int t = (threadIdx.x >= d) ? s[threadIdx.x - d] : 0;
        __syncthreads();
        s[threadIdx.x] += t;
        __syncthreads();
    }
    if (i < N) offs[i] = s[threadIdx.x] - v;   // exclusive
    if (threadIdx.x == 255) bsum[blockIdx.x] = s[255];
}

__global__ __launch_bounds__(256) void scan_bsum(int* __restrict__ bsum, int nb)
{
    __shared__ int s[256];
    int v = (threadIdx.x < nb) ? bsum[threadIdx.x] : 0;
    s[threadIdx.x] = v;
    __syncthreads();
    for (int d = 1; d < 256; d <<= 1) {
        int t = (threadIdx.x >= d) ? s[threadIdx.x - d] : 0;
        __syncthreads();
        s[threadIdx.x] += t;
        __syncthreads();
    }
    if (threadIdx.x < nb) bsum[threadIdx.x] = s[threadIdx.x] - v;  // exclusive
}

__global__ __launch_bounds__(256) void add_offs(
    int* __restrict__ offs, int* __restrict__ cursor,
    const int* __restrict__ bsum, int N, int E)
{
    int i = blockIdx.x * 256 + threadIdx.x;
    if (i < N) {
        int f = offs[i] + bsum[blockIdx.x];
        offs[i] = f;
        cursor[i] = f;
    }
    if (i == 0) offs[N] = E;
}

// materialize CSR-ordered source index + log(nw): kills the 3-hop chase in attn
__global__ __launch_bounds__(256) void fill_kernel(
    const int* __restrict__ tgt, const int* __restrict__ src,
    const float* __restrict__ nw_i, const float* __restrict__ nw_a,
    int* __restrict__ cur_i, int* __restrict__ cur_a,
    int* __restrict__ src_i, float* __restrict__ lw_i,
    int* __restrict__ src_a, float* __restrict__ lw_a, int E)
{
    int e = blockIdx.x * 256 + threadIdx.x;
    if (e < E) {
        int t = tgt[e], s = src[e];
        float li = logf(fmaxf(nw_i[e], 1e-10f));
        float la = logf(fmaxf(nw_a[e], 1e-10f));
        int p = atomicAdd(&cur_i[t], 1);
        src_i[p] = s; lw_i[p] = li;
        int q = atomicAdd(&cur_a[s], 1);
        src_a[q] = t; lw_a[q] = la;
    }
}

// ================= weight prep: f32 W[K][256] -> packed B fragments =================
struct PrepArgs {
    const float* src[7];
    unsigned short* hi[7];
    unsigned short* lo[7];
    int K[7];
    int off[8];   // slot offsets; slots per matrix = (K/16)*8*64
};

__global__ __launch_bounds__(256) void prep_w(PrepArgs a)
{
    int s = blockIdx.x * 256 + threadIdx.x;
    if (s >= a.off[7]) return;
    int m = 0;
    #pragma unroll
    for (int i = 0; i < 6; ++i) m += (s >= a.off[i + 1]) ? 1 : 0;
    int sl = s - a.off[m];
    int KB = a.K[m] >> 4;
    int l  = sl & 63;
    int kb = (sl >> 6) % KB;
    int nb = (sl >> 6) / KB;
    int n  = nb * 32 + (l & 31);
    int k0 = kb * 16 + ((l >> 5) << 3);
    ushort8 hh, ll;
    #pragma unroll
    for (int i = 0; i < 8; ++i) {
        float x = a.src[m][(size_t)(k0 + i) * 256 + n];
        __bf16 h = (__bf16)x;
        hh[i] = __builtin_bit_cast(unsigned short, h);
        ll[i] = __builtin_bit_cast(unsigned short, (__bf16)(x - (float)h));
    }
    *(ushort8*)(a.hi[m] + (size_t)sl * 8) = hh;
    *(ushort8*)(a.lo[m] + (size_t)sl * 8) = ll;
}

// ================= row pack: f32 X[M][256] -> packed A fragments =================
__global__ __launch_bounds__(256) void pack_rows(
    const float* __restrict__ X, unsigned short* __restrict__ Ph,
    unsigned short* __restrict__ Pl, int M, int RB)
{
    int s = blockIdx.x * 256 + threadIdx.x;
    int total = RB * 16 * 64;
    if (s >= total) return;
    int l  = s & 63;
    int kb = (s >> 6) & 15;
    int rb = s >> 10;
    int row = min(rb * 32 + (l & 31), M - 1);
    int k0  = kb * 16 + ((l >> 5) << 3);
    const float* p = X + (size_t)row * 256 + k0;
    float4 f0 = *(const float4*)p;
    float4 f1 = *(const float4*)(p + 4);
    float xs[8] = {f0.x, f0.y, f0.z, f0.w, f1.x, f1.y, f1.z, f1.w};
    ushort8 hh, ll;
    #pragma unroll
    for (int i = 0; i < 8; ++i) {
        __bf16 h = (__bf16)xs[i];
        hh[i] = __builtin_bit_cast(unsigned short, h);
        ll[i] = __builtin_bit_cast(unsigned short, (__bf16)(xs[i] - (float)h));
    }
    *(ushort8*)(Ph + (size_t)s * 8) = hh;
    *(ushort8*)(Pl + (size_t)s * 8) = ll;
}

// ================= fused per-target attention =================
// CSR-ordered srcs/lws (1-hop gather), depth-2 meta / depth-1 row prefetch.
// msg written directly in packed A-fragment hi/lo form (identical numerics).
__global__ __launch_bounds__(256) void fused_attn(
    const float* __restrict__ Q, const float* __restrict__ Kk, const float* __restrict__ V,
    const int* __restrict__ offs, const int* __restrict__ srcs,
    const float* __restrict__ lws,
    float* __restrict__ scbuf, unsigned short* __restrict__ msgH,
    unsigned short* __restrict__ msgL, int T)
{
    int w = blockIdx.x * 4 + (threadIdx.x >> 6);
    int lane = threadIdx.x & 63;
    if (w >= T) return;
    int t = w;
    int beg = offs[t], end = offs[t + 1];
    int h = lane >> 4;

    float4 q = *(const float4*)(Q + (size_t)t * 256 + lane * 4);

    // ---- pass 1: scores + running max ----
    float mx = 0.f;   // 0-init matches torch scatter amax include_self with zeros
    {
        int sN = 0; float lC = 0.f, lN = 0.f;
        float4 k0 = make_float4(0.f, 0.f, 0.f, 0.f);
        if (beg < end) {
            int s0 = srcs[beg];
            lC = lws[beg];
            k0 = *(const float4*)(Kk + (size_t)s0 * 256 + lane * 4);
        }
        if (beg + 1 < end) { sN = srcs[beg + 1]; lN = lws[beg + 1]; }
        for (int j = beg; j < end; ++j) {
            int sNN = 0; float lNN = 0.f;
            if (j + 2 < end) { sNN = srcs[j + 2]; lNN = lws[j + 2]; }
            float4 k1 = k0;
            if (j + 1 < end) k1 = *(const float4*)(Kk + (size_t)sN * 256 + lane * 4);
            float d = q.x * k0.x + q.y * k0.y + q.z * k0.z + q.w * k0.w;
            d += __shfl_xor(d, 1);
            d += __shfl_xor(d, 2);
            d += __shfl_xor(d, 4);
            d += __shfl_xor(d, 8);
            float sc = d * 0.125f + lC;
            if ((lane & 15) == 0) scbuf[(size_t)j * 4 + h] = sc;
            mx = fmaxf(mx, sc);
            k0 = k1; lC = lN; sN = sNN; lN = lNN;
        }
    }

    // ---- pass 2: exp/sum + ex*V accumulate ----
    float sum = 0.f;
    float4 macc = make_float4(0.f, 0.f, 0.f, 0.f);
    {
        int sN = 0; float scC = 0.f, scN = 0.f;
        float4 v0 = make_float4(0.f, 0.f, 0.f, 0.f);
        if (beg < end) {
            int s0 = srcs[beg];
            scC = scbuf[(size_t)beg * 4 + h];
            v0 = *(const float4*)(V + (size_t)s0 * 256 + lane * 4);
        }
        if (beg + 1 < end) { sN = srcs[beg + 1]; scN = scbuf[(size_t)(beg + 1) * 4 + h]; }
        for (int j = beg; j < end; ++j) {
            int sNN = 0; float scNN = 0.f;
            if (j + 2 < end) { sNN = srcs[j + 2]; scNN = scbuf[(size_t)(j + 2) * 4 + h]; }
            float4 v1 = v0;
            if (j + 1 < end) v1 = *(const float4*)(V + (size_t)sN * 256 + lane * 4);
            float ex = expf(scC - mx);
            sum += ex;
            macc.x += ex * v0.x; macc.y += ex * v0.y;
            macc.z += ex * v0.z; macc.w += ex * v0.w;
            v0 = v1; scC = scN; sN = sNN; scN = scNN;
        }
    }
    float inv = 1.f / (sum + 1e-10f);
    float vals[4] = {macc.x * inv, macc.y * inv, macc.z * inv, macc.w * inv};
    unsigned short hs[4], ls[4];
    #pragma unroll
    for (int i = 0; i < 4; ++i) {
        __bf16 hh = (__bf16)vals[i];
        hs[i] = __builtin_bit_cast(unsigned short, hh);
        ls[i] = __builtin_bit_cast(unsigned short, (__bf16)(vals[i] - (float)hh));
    }
    // packed slot: cols c = 4*lane..4*lane+3 of row t
    size_t base = (((size_t)(t >> 5) * 16 + (lane >> 2)) * 64 + ((lane >> 1) & 1) * 32 + (t & 31)) * 8
                + ((lane & 1) << 2);
    *(ushort4*)(msgH + base) = make_ushort4(hs[0], hs[1], hs[2], hs[3]);
    *(ushort4*)(msgL + base) = make_ushort4(ls[0], ls[1], ls[2], ls[3]);
}

// ================= packed-operand MFMA bf16x3 GEMM, async-LDS 2-phase =================
// C = act(A @ W + bias). Block = 128 rows x 128 cols (grid.y=2), 4 waves 2x2,
// wave = 64x64 = 2x2 subtiles of 32x32. A hi/lo staged via global_load_lds into a
// double-buffered 64 KB LDS (BK=64 = 4 kb-steps/stage); stage st+1 issued BEFORE
// computing stage st; one barrier (vmcnt drain) per stage (T3-minimal pipeline).
// B fragments are L2-hot register loads. Epilogue: per-wave LDS transpose (union'd).
template<int CONCAT, int PACKOUT>
__global__ __launch_bounds__(256, 2) void gemm_pk(
    const unsigned short* __restrict__ Ah, const unsigned short* __restrict__ Al,
    const unsigned short* __restrict__ A2h, const unsigned short* __restrict__ A2l,
    const unsigned short* __restrict__ Bh, const unsigned short* __restrict__ Bl,
    const float* __restrict__ bias, int act, int M,
    float* __restrict__ Cf, unsigned short* __restrict__ Ch, unsigned short* __restrict__ Cl)
{
    const int KB = CONCAT ? 32 : 16;     // B k-blocks
    const int KT = CONCAT ? 32 : 16;     // total kb steps
    const int NS = KT / 4;               // stages (BK=64)
    const int RB = (M + 31) >> 5;
    const int lane = threadIdx.x & 63;
    const int w = threadIdx.x >> 6;
    const int wm = w >> 1, wn = w & 1;
    const int rbb = blockIdx.x * 4;
    const int nb0 = blockIdx.y * 4 + wn * 2;

    __shared__ union {
        unsigned short stage[2][2][4][4][512];  // [buf][half][rb][kb][lane*8] = 64 KB
        float tbuf[4][32 * 33];
    } sm __attribute__((aligned(16)));

    f32x16 acc[2][2] = {};

    // staging unit u (0..31): half=u>>4, rb=(u>>2)&3, kb=u&3; wave w issues u=w*8..w*8+7
    auto stage_one = [&](int buf, int st, int u) {
        int half = u >> 4, rb = (u >> 2) & 3, kb = u & 3;
        int kbg = st * 4 + kb;
        const unsigned short* srcp;
        int kba = kbg;
        if (CONCAT && kbg >= 16) { kba = kbg - 16; srcp = half ? A2l : A2h; }
        else                     { srcp = half ? Al : Ah; }
        int rbl = min(rbb + rb, RB - 1);
        const unsigned short* g = srcp + ((size_t)(rbl * 16 + kba) * 64 + lane) * 8;
        gload_lds16(g, &sm.stage[buf][half][rb][kb][0]);
    };

    auto comp_kb = [&](int buf, int st, int kb) {
        int kbg = st * 4 + kb;
        const int rA = wm * 2;
        bf16x8 a0h = __builtin_bit_cast(bf16x8, *(const ushort8*)&sm.stage[buf][0][rA + 0][kb][lane * 8]);
        bf16x8 a0l = __builtin_bit_cast(bf16x8, *(const ushort8*)&sm.stage[buf][1][rA + 0][kb][lane * 8]);
        bf16x8 a1h = __builtin_bit_cast(bf16x8, *(const ushort8*)&sm.stage[buf][0][rA + 1][kb][lane * 8]);
        bf16x8 a1l = __builtin_bit_cast(bf16x8, *(const ushort8*)&sm.stage[buf][1][rA + 1][kb][lane * 8]);
        size_t t0 = ((size_t)((nb0 + 0) * KB + kbg) * 64 + lane) * 8;
        size_t t1 = ((size_t)((nb0 + 1) * KB + kbg) * 64 + lane) * 8;
        bf16x8 b0h = __builtin_bit_cast(bf16x8, *(const ushort8*)(Bh + t0));
        bf16x8 b0l = __builtin_bit_cast(bf16x8, *(const ushort8*)(Bl + t0));
        bf16x8 b1h = __builtin_bit_cast(bf16x8, *(const ushort8*)(Bh + t1));
        bf16x8 b1l = __builtin_bit_cast(bf16x8, *(const ushort8*)(Bl + t1));
        acc[0][0] = __builtin_amdgcn_mfma_f32_32x32x16_bf16(a0h, b0h, acc[0][0], 0, 0, 0);
        acc[0][0] = __builtin_amdgcn_mfma_f32_32x32x16_bf16(a0h, b0l, acc[0][0], 0, 0, 0);
        acc[0][0] = __builtin_amdgcn_mfma_f32_32x32x16_bf16(a0l, b0h, acc[0][0], 0, 0, 0);
        acc[0][1] = __builtin_amdgcn_mfma_f32_32x32x16_bf16(a0h, b1h, acc[0][1], 0, 0, 0);
        acc[0][1] = __builtin_amdgcn_mfma_f32_32x32x16_bf16(a0h, b1l, acc[0][1], 0, 0, 0);
        acc[0][1] = __builtin_amdgcn_mfma_f32_32x32x16_bf16(a0l, b1h, acc[0][1], 0, 0, 0);
        acc[1][0] = __builtin_amdgcn_mfma_f32_32x32x16_bf16(a1h, b0h, acc[1][0], 0, 0, 0);
        acc[1][0] = __builtin_amdgcn_mfma_f32_32x32x16_bf16(a1h, b0l, acc[1][0], 0, 0, 0);
        acc[1][0] = __builtin_amdgcn_mfma_f32_32x32x16_bf16(a1l, b0h, acc[1][0], 0, 0, 0);
        acc[1][1] = __builtin_amdgcn_mfma_f32_32x32x16_bf16(a1h, b1h, acc[1][1], 0, 0, 0);
        acc[1][1] = __builtin_amdgcn_mfma_f32_32x32x16_bf16(a1h, b1l, acc[1][1], 0, 0, 0);
        acc[1][1] = __builtin_amdgcn_mfma_f32_32x32x16_bf16(a1l, b1h, acc[1][1], 0, 0, 0);
    };

    // prologue: stage 0
    #pragma unroll
    for (int i = 0; i < 8; ++i) stage_one(0, 0, w * 8 + i);
    __syncthreads();

    int buf = 0;
    for (int st = 0; st < NS; ++st) {
        if (st + 1 < NS) {
            #pragma unroll
            for (int i = 0; i < 8; ++i) stage_one(buf ^ 1, st + 1, w * 8 + i);
        }
        #pragma unroll
        for (int kb = 0; kb < 4; ++kb) comp_kb(buf, st, kb);
        __syncthreads();   // drains this wave's stage loads (vmcnt 0) + barrier
        buf ^= 1;
    }

    // ---- epilogue: bias + act, per-wave LDS transpose (reuses union), stores ----
    const int m2 = lane & 31;
    #pragma unroll
    for (int mt = 0; mt < 2; ++mt) {
        int rb = rbb + wm * 2 + mt;
        bool rvalid = rb < RB;
        int mg = rb * 32 + m2;
        #pragma unroll
        for (int nt = 0; nt < 2; ++nt) {
            int nb = nb0 + nt;
            float bv = bias ? bias[nb * 32 + (lane & 31)] : 0.f;
            #pragma unroll
            for (int r = 0; r < 16; ++r) {
                int ml = (r & 3) + ((r >> 2) << 3) + ((lane >> 5) << 2);
                float v = acc[mt][nt][r] + bv;
                if (act) v = gelu_exact(v);
                sm.tbuf[w][ml * 33 + (lane & 31)] = v;
            }
            asm volatile("s_waitcnt lgkmcnt(0)" ::: "memory");
            #pragma unroll
            for (int qq = 0; qq < 2; ++qq) {
                int c0 = ((lane >> 5) << 3) + (qq << 4);   // 0,8,16,24 local col
                float vs[8];
                #pragma unroll
                for (int i = 0; i < 8; ++i) vs[i] = sm.tbuf[w][m2 * 33 + c0 + i];
                if (PACKOUT) {
                    ushort8 hh, ll;
                    #pragma unroll
                    for (int i = 0; i < 8; ++i) {
                        __bf16 hb = (__bf16)vs[i];
                        hh[i] = __builtin_bit_cast(unsigned short, hb);
                        ll[i] = __builtin_bit_cast(unsigned short, (__bf16)(vs[i] - (float)hb));
                    }
                    int ng = nb * 32 + c0;
                    size_t slot = (((size_t)rb * 16 + (ng >> 4)) * 64 + ((ng >> 3) & 1) * 32 + m2) * 8;
                    if (rvalid) {
                        *(ushort8*)(Ch + slot) = hh;
                        *(ushort8*)(Cl + slot) = ll;
                    }
                } else {
                    if (mg < M) {
                        float* cp = Cf + (size_t)mg * 256 + nb * 32 + c0;
                        *(float4*)(cp)     = make_float4(vs[0], vs[1], vs[2], vs[3]);
                        *(float4*)(cp + 4) = make_float4(vs[4], vs[5], vs[6], vs[7]);
                    }
                }
            }
            asm volatile("s_waitcnt lgkmcnt(0)" ::: "memory");  // tbuf reuse safe (same wave)
        }
    }
}

// ================= host =================
extern "C" void kernel_launch(void* const* d_in, const int* in_sizes, int n_in,
                              void* d_out, int out_size, void* d_ws, size_t ws_size,
                              hipStream_t stream) {
    const float* inv_h    = (const float*)d_in[0];
    const float* asset_h  = (const float*)d_in[1];
    const float* inv_nw   = (const float*)d_in[2];
    const float* asset_nw = (const float*)d_in[3];
    const float* m_w1 = (const float*)d_in[4];
    const float* m_b1 = (const float*)d_in[5];
    const float* m_w2 = (const float*)d_in[6];
    const float* m_b2 = (const float*)d_in[7];
    const float* Wq   = (const float*)d_in[8];
    const float* Wk   = (const float*)d_in[9];
    const float* Wv   = (const float*)d_in[10];
    const float* u_w1 = (const float*)d_in[11];
    const float* u_b1 = (const float*)d_in[12];
    const float* u_w2 = (const float*)d_in[13];
    const float* u_b2 = (const float*)d_in[14];
    const int* etgt  = (const int*)d_in[15];
    const int* esrc  = (const int*)d_in[16];

    const int I = in_sizes[0] / 256;
    const int A = in_sizes[1] / 256;
    const int E = in_sizes[15];
    const int RBI = (I + 31) >> 5;
    const int RBA = (A + 31) >> 5;

    float* out_inv   = (float*)d_out;
    float* out_asset = (float*)d_out + (size_t)I * 256;

    char* wsp = (char*)d_ws;
    size_t off = 0;
    auto alloc = [&](size_t bytes) -> char* {
        char* p = wsp + off;
        off += (bytes + 255) & ~(size_t)255;
        return p;
    };

    const size_t ipackHalf = (size_t)RBI * 16384;  // bytes per half (hi or lo)
    const size_t apackHalf = (size_t)RBA * 16384;
    const size_t if32 = (size_t)I * 1024;
    const size_t af32 = (size_t)A * 1024;
    const size_t r_sz = (2 * ipackHalf > if32) ? 2 * ipackHalf : if32;
    const size_t s_sz = (2 * apackHalf > af32) ? 2 * apackHalf : af32;

    unsigned short* invP_h  = (unsigned short*)alloc(ipackHalf);
    unsigned short* invP_l  = (unsigned short*)alloc(ipackHalf);
    unsigned short* astP_h  = (unsigned short*)alloc(apackHalf);
    unsigned short* astP_l  = (unsigned short*)alloc(apackHalf);
    char* R1 = alloc(r_sz);   // tP_i pack | V_i f32 | Q_i f32 | hidP_i pack
    char* R2 = alloc(r_sz);   // MP_i pack | K_i f32 | msgP_i pack
    char* S1 = alloc(s_sz);   // Q_a f32 | tP_a pack | V_a f32
    char* S2 = alloc(s_sz);   // msgP_a pack | MP_a pack | K_a f32
    char* S3 = alloc(s_sz);   // hidP_a pack
    float* scbuf = (float*)alloc((size_t)E * 4 * 4);
    int* cnt_i  = (int*)alloc((size_t)I * 4);
    int* cnt_a  = (int*)alloc((size_t)A * 4);
    int* offs_i = (int*)alloc((size_t)(I + 1) * 4);
    int* offs_a = (int*)alloc((size_t)(A + 1) * 4);
    int* gsrc_i = (int*)alloc((size_t)E * 4);
    int* gsrc_a = (int*)alloc((size_t)E * 4);
    float* glw_i = (float*)alloc((size_t)E * 4);
    float* glw_a = (float*)alloc((size_t)E * 4);
    int* bsum_i = (int*)alloc(256 * 4);
    int* bsum_a = (int*)alloc(256 * 4);

    // weight packs
    PrepArgs pa;
    const float* wsrc[7] = {m_w1, m_w2, Wq, Wk, Wv, u_w1, u_w2};
    const int    wK[7]   = {256, 256, 256, 256, 256, 512, 256};
    unsigned short* wph[7];
    unsigned short* wpl[7];
    pa.off[0] = 0;
    for (int i = 0; i < 7; ++i) {
        size_t slots = (size_t)(wK[i] >> 4) * 8 * 64;
        wph[i] = (unsigned short*)alloc(slots * 16);
        wpl[i] = (unsigned short*)alloc(slots * 16);
        pa.src[i] = wsrc[i];
        pa.hi[i] = wph[i];
        pa.lo[i] = wpl[i];
        pa.K[i] = wK[i];
        pa.off[i + 1] = pa.off[i] + (int)slots;
    }

    const int nbI = (I + 255) / 256;
    const int nbA = (A + 255) / 256;
    const int nbE = (E + 255) / 256;

    // ---- operand prep ----
    hipLaunchKernelGGL(prep_w, dim3((pa.off[7] + 255) / 256), dim3(256), 0, stream, pa);
    hipLaunchKernelGGL(pack_rows, dim3((RBI * 1024 + 255) / 256), dim3(256), 0, stream,
                       inv_h, invP_h, invP_l, I, RBI);
    hipLaunchKernelGGL(pack_rows, dim3((RBA * 1024 + 255) / 256), dim3(256), 0, stream,
                       asset_h, astP_h, astP_l, A, RBA);

    // ---- CSR build ----
    hipMemsetAsync(cnt_i, 0, (size_t)I * 4, stream);
    hipMemsetAsync(cnt_a, 0, (size_t)A * 4, stream);
    hipLaunchKernelGGL(count_kernel, dim3(nbE), dim3(256), 0, stream,
                       etgt, esrc, cnt_i, cnt_a, E);
    hipLaunchKernelGGL(scan_block, dim3(nbI), dim3(256), 0, stream, cnt_i, offs_i, bsum_i, I);
    hipLaunchKernelGGL(scan_block, dim3(nbA), dim3(256), 0, stream, cnt_a, offs_a, bsum_a, A);
    hipLaunchKernelGGL(scan_bsum, dim3(1), dim3(256), 0, stream, bsum_i, nbI);
    hipLaunchKernelGGL(scan_bsum, dim3(1), dim3(256), 0, stream, bsum_a, nbA);
    hipLaunchKernelGGL(add_offs, dim3(nbI), dim3(256), 0, stream, offs_i, cnt_i, bsum_i, I, E);
    hipLaunchKernelGGL(add_offs, dim3(nbA), dim3(256), 0, stream, offs_a, cnt_a, bsum_a, A, E);
    hipLaunchKernelGGL(fill_kernel, dim3(nbE), dim3(256), 0, stream,
                       etgt, esrc, inv_nw, asset_nw, cnt_i, cnt_a,
                       gsrc_i, glw_i, gsrc_a, glw_a, E);

    // gemm launcher. outmode: 0 = f32 Cf, 1 = packed (cH,cL)
    auto gemm = [&](const unsigned short* aH, const unsigned short* aL,
                    const unsigned short* a2H, const unsigned short* a2L,
                    int M, int widx, const float* bias, int act,
                    float* cf, unsigned short* cH, unsigned short* cL, int concat) {
        dim3 grid((((M + 31) >> 5) + 3) / 4, 2);
        if (concat) {
            if (cf) hipLaunchKernelGGL((gemm_pk<1,0>), grid, dim3(256), 0, stream,
                        aH, aL, a2H, a2L, wph[widx], wpl[widx], bias, act, M, cf, cH, cL);
            else    hipLaunchKernelGGL((gemm_pk<1,1>), grid, dim3(256), 0, stream,
                        aH, aL, a2H, a2L, wph[widx], wpl[widx], bias, act, M, cf, cH, cL);
        } else {
            if (cf) hipLaunchKernelGGL((gemm_pk<0,0>), grid, dim3(256), 0, stream,
                        aH, aL, a2H, a2L, wph[widx], wpl[widx], bias, act, M, cf, cH, cL);
            else    hipLaunchKernelGGL((gemm_pk<0,1>), grid, dim3(256), 0, stream,
                        aH, aL, a2H, a2L, wph[widx], wpl[widx], bias, act, M, cf, cH, cL);
        }
    };
    // widx: 0=m_w1 1=m_w2 2=Wq 3=Wk 4=Wv 5=u_w1 6=u_w2

    auto ph = [&](char* r) { return (unsigned short*)r; };
    auto plI = [&](char* r) { return (unsigned short*)(r + ipackHalf); };
    auto plA = [&](char* r) { return (unsigned short*)(r + apackHalf); };

    // ===== direction 2: assets aggregate from investors =====
    gemm(invP_h, invP_l, 0, 0, I, 0, m_b1, 1, nullptr, ph(R1), plI(R1), 0);   // tP_i -> R1
    gemm(ph(R1), plI(R1), 0, 0, I, 1, m_b2, 1, nullptr, ph(R2), plI(R2), 0);  // MP_i -> R2
    gemm(ph(R2), plI(R2), 0, 0, I, 4, nullptr, 0, (float*)R1, 0, 0, 0);       // V_i f32 -> R1
    gemm(invP_h, invP_l, 0, 0, I, 3, nullptr, 0, (float*)R2, 0, 0, 0);        // K_i f32 -> R2
    gemm(astP_h, astP_l, 0, 0, A, 2, nullptr, 0, (float*)S1, 0, 0, 0);        // Q_a f32 -> S1

    hipLaunchKernelGGL(fused_attn, dim3((A + 3) / 4), dim3(256), 0, stream,
                       (float*)S1, (float*)R2, (float*)R1, offs_a, gsrc_a, glw_a,
                       scbuf, ph(S2), plA(S2), A);                            // msgP_a -> S2

    gemm(astP_h, astP_l, ph(S2), plA(S2), A, 5, u_b1, 1, nullptr, ph(S3), plA(S3), 1); // hidP_a -> S3
    gemm(ph(S3), plA(S3), 0, 0, A, 6, u_b2, 1, out_asset, 0, 0, 0);

    // ===== direction 1: investors aggregate from assets =====
    gemm(astP_h, astP_l, 0, 0, A, 0, m_b1, 1, nullptr, ph(S1), plA(S1), 0);   // tP_a -> S1
    gemm(ph(S1), plA(S1), 0, 0, A, 1, m_b2, 1, nullptr, ph(S2), plA(S2), 0);  // MP_a -> S2
    gemm(ph(S2), plA(S2), 0, 0, A, 4, nullptr, 0, (float*)S1, 0, 0, 0);       // V_a f32 -> S1
    gemm(astP_h, astP_l, 0, 0, A, 3, nullptr, 0, (float*)S2, 0, 0, 0);        // K_a f32 -> S2
    gemm(invP_h, invP_l, 0, 0, I, 2, nullptr, 0, (float*)R1, 0, 0, 0);        // Q_i f32 -> R1

    hipLaunchKernelGGL(fused_attn, dim3((I + 3) / 4), dim3(256), 0, stream,
                       (float*)R1, (float*)S2, (float*)S1, offs_i, gsrc_i, glw_i,
                       scbuf, ph(R2), plI(R2), I);                            // msgP_i -> R2

    gemm(invP_h, invP_l, ph(R2), plI(R2), I, 5, u_b1, 1, nullptr, ph(R1), plI(R1), 1); // hidP_i -> R1
    gemm(ph(R1), plI(R1), 0, 0, I, 6, u_b2, 1, out_inv, 0, 0, 0);
}

// Round 5
// 835.908 us; speedup vs baseline: 1.5759x; 1.3221x over previous
//
#include <hip/hip_runtime.h>

typedef __bf16 bf16x8 __attribute__((ext_vector_type(8)));
typedef float f32x16 __attribute__((ext_vector_type(16)));
typedef unsigned short ushort8 __attribute__((ext_vector_type(8)));

// ---------- helpers ----------
__device__ __forceinline__ float gelu_exact(float x) {
    return 0.5f * x * (1.0f + erff(x * 0.70710678118654752440f));
}

// async global->LDS, 16B per lane; dest is wave-uniform base, HW adds lane*16
__device__ __forceinline__ void gload_lds16(const void* g, void* l) {
    __builtin_amdgcn_global_load_lds(
        (const __attribute__((address_space(1))) unsigned int*)g,
        (__attribute__((address_space(3))) unsigned int*)l, 16, 0, 0);
}

// =====================================================================
// Packed operand layout (bf16 hi/lo, MFMA-fragment-linear):
//   A-pack for [M][256]: slot s = (rb*16 + kb)*64 + lane, 8 ushorts each.
//     lane's elems = A[rb*32 + (lane&31)][kb*16 + (lane>>5)*8 + i], i=0..7
//   B-pack for W[K][256]: slot = (nb*KB + kb)*64 + lane, KB = K/16.
//     lane's elems = W[kb*16 + (lane>>5)*8 + i][nb*32 + (lane&31)]
//   One fragment = 1 KB contiguous per wave -> exactly one global_load_lds.
// =====================================================================

// ================= CSR build =================
__global__ __launch_bounds__(256) void count_kernel(
    const int* __restrict__ tgt, const int* __restrict__ src,
    int* __restrict__ cnt_i, int* __restrict__ cnt_a, int E)
{
    int e = blockIdx.x * 256 + threadIdx.x;
    if (e < E) {
        atomicAdd(&cnt_i[tgt[e]], 1);
        atomicAdd(&cnt_a[src[e]], 1);
    }
}

__global__ __launch_bounds__(256) void scan_block(
    const int* __restrict__ cnt, int* __restrict__ offs, int* __restrict__ bsum, int N)
{
    __shared__ int s[256];
    int i = blockIdx.x * 256 + threadIdx.x;
    int v = (i < N) ? cnt[i] : 0;
    s[threadIdx.x] = v;
    __syncthreads();
    for (int d = 1; d < 256; d <<= 1) {
        int t = (threadIdx.x >= d) ? s[threadIdx.x - d] : 0;
        __syncthreads();
        s[threadIdx.x] += t;
        __syncthreads();
    }
    if (i < N) offs[i] = s[threadIdx.x] - v;   // exclusive
    if (threadIdx.x == 255) bsum[blockIdx.x] = s[255];
}

__global__ __launch_bounds__(256) void scan_bsum(int* __restrict__ bsum, int nb)
{
    __shared__ int s[256];
    int v = (threadIdx.x < nb) ? bsum[threadIdx.x] : 0;
    s[threadIdx.x] = v;
    __syncthreads();
    for (int d = 1; d < 256; d <<= 1) {
        int t = (threadIdx.x >= d) ? s[threadIdx.x - d] : 0;
        __syncthreads();
        s[threadIdx.x] += t;
        __syncthreads();
    }
    if (threadIdx.x < nb) bsum[threadIdx.x] = s[threadIdx.x] - v;  // exclusive
}

__global__ __launch_bounds__(256) void add_offs(
    int* __restrict__ offs, int* __restrict__ cursor,
    const int* __restrict__ bsum, int N, int E)
{
    int i = blockIdx.x * 256 + threadIdx.x;
    if (i < N) {
        int f = offs[i] + bsum[blockIdx.x];
        offs[i] = f;
        cursor[i] = f;
    }
    if (i == 0) offs[N] = E;
}

// materialize CSR-ordered source index + log(nw): kills the 3-hop chase in attn
__global__ __launch_bounds__(256) void fill_kernel(
    const int* __restrict__ tgt, const int* __restrict__ src,
    const float* __restrict__ nw_i, const float* __restrict__ nw_a,
    int* __restrict__ cur_i, int* __restrict__ cur_a,
    int* __restrict__ src_i, float* __restrict__ lw_i,
    int* __restrict__ src_a, float* __restrict__ lw_a, int E)
{
    int e = blockIdx.x * 256 + threadIdx.x;
    if (e < E) {
        int t = tgt[e], s = src[e];
        float li = logf(fmaxf(nw_i[e], 1e-10f));
        float la = logf(fmaxf(nw_a[e], 1e-10f));
        int p = atomicAdd(&cur_i[t], 1);
        src_i[p] = s; lw_i[p] = li;
        int q = atomicAdd(&cur_a[s], 1);
        src_a[q] = t; lw_a[q] = la;
    }
}

// ================= weight prep: f32 W[K][256] -> packed B fragments =================
struct PrepArgs {
    const float* src[7];
    unsigned short* hi[7];
    unsigned short* lo[7];
    int K[7];
    int off[8];   // slot offsets; slots per matrix = (K/16)*8*64
};

__global__ __launch_bounds__(256) void prep_w(PrepArgs a)
{
    int s = blockIdx.x * 256 + threadIdx.x;
    if (s >= a.off[7]) return;
    int m = 0;
    #pragma unroll
    for (int i = 0; i < 6; ++i) m += (s >= a.off[i + 1]) ? 1 : 0;
    int sl = s - a.off[m];
    int KB = a.K[m] >> 4;
    int l  = sl & 63;
    int kb = (sl >> 6) % KB;
    int nb = (sl >> 6) / KB;
    int n  = nb * 32 + (l & 31);
    int k0 = kb * 16 + ((l >> 5) << 3);
    ushort8 hh, ll;
    #pragma unroll
    for (int i = 0; i < 8; ++i) {
        float x = a.src[m][(size_t)(k0 + i) * 256 + n];
        __bf16 h = (__bf16)x;
        hh[i] = __builtin_bit_cast(unsigned short, h);
        ll[i] = __builtin_bit_cast(unsigned short, (__bf16)(x - (float)h));
    }
    *(ushort8*)(a.hi[m] + (size_t)sl * 8) = hh;
    *(ushort8*)(a.lo[m] + (size_t)sl * 8) = ll;
}

// ================= row pack: f32 X[M][256] -> packed A fragments =================
__global__ __launch_bounds__(256) void pack_rows(
    const float* __restrict__ X, unsigned short* __restrict__ Ph,
    unsigned short* __restrict__ Pl, int M, int RB)
{
    int s = blockIdx.x * 256 + threadIdx.x;
    int total = RB * 16 * 64;
    if (s >= total) return;
    int l  = s & 63;
    int kb = (s >> 6) & 15;
    int rb = s >> 10;
    int row = min(rb * 32 + (l & 31), M - 1);
    int k0  = kb * 16 + ((l >> 5) << 3);
    const float* p = X + (size_t)row * 256 + k0;
    float4 f0 = *(const float4*)p;
    float4 f1 = *(const float4*)(p + 4);
    float xs[8] = {f0.x, f0.y, f0.z, f0.w, f1.x, f1.y, f1.z, f1.w};
    ushort8 hh, ll;
    #pragma unroll
    for (int i = 0; i < 8; ++i) {
        __bf16 h = (__bf16)xs[i];
        hh[i] = __builtin_bit_cast(unsigned short, h);
        ll[i] = __builtin_bit_cast(unsigned short, (__bf16)(xs[i] - (float)h));
    }
    *(ushort8*)(Ph + (size_t)s * 8) = hh;
    *(ushort8*)(Pl + (size_t)s * 8) = ll;
}

// ================= fused per-target attention =================
// CSR-ordered srcs/lws (1-hop gather), depth-2 meta / depth-1 row prefetch.
// msg written directly in packed A-fragment hi/lo form (identical numerics).
__global__ __launch_bounds__(256) void fused_attn(
    const float* __restrict__ Q, const float* __restrict__ Kk, const float* __restrict__ V,
    const int* __restrict__ offs, const int* __restrict__ srcs,
    const float* __restrict__ lws,
    float* __restrict__ scbuf, unsigned short* __restrict__ msgH,
    unsigned short* __restrict__ msgL, int T)
{
    int w = blockIdx.x * 4 + (threadIdx.x >> 6);
    int lane = threadIdx.x & 63;
    if (w >= T) return;
    int t = w;
    int beg = offs[t], end = offs[t + 1];
    int h = lane >> 4;

    float4 q = *(const float4*)(Q + (size_t)t * 256 + lane * 4);

    // ---- pass 1: scores + running max ----
    float mx = 0.f;   // 0-init matches torch scatter amax include_self with zeros
    {
        int sN = 0; float lC = 0.f, lN = 0.f;
        float4 k0 = make_float4(0.f, 0.f, 0.f, 0.f);
        if (beg < end) {
            int s0 = srcs[beg];
            lC = lws[beg];
            k0 = *(const float4*)(Kk + (size_t)s0 * 256 + lane * 4);
        }
        if (beg + 1 < end) { sN = srcs[beg + 1]; lN = lws[beg + 1]; }
        for (int j = beg; j < end; ++j) {
            int sNN = 0; float lNN = 0.f;
            if (j + 2 < end) { sNN = srcs[j + 2]; lNN = lws[j + 2]; }
            float4 k1 = k0;
            if (j + 1 < end) k1 = *(const float4*)(Kk + (size_t)sN * 256 + lane * 4);
            float d = q.x * k0.x + q.y * k0.y + q.z * k0.z + q.w * k0.w;
            d += __shfl_xor(d, 1);
            d += __shfl_xor(d, 2);
            d += __shfl_xor(d, 4);
            d += __shfl_xor(d, 8);
            float sc = d * 0.125f + lC;
            if ((lane & 15) == 0) scbuf[(size_t)j * 4 + h] = sc;
            mx = fmaxf(mx, sc);
            k0 = k1; lC = lN; sN = sNN; lN = lNN;
        }
    }

    // ---- pass 2: exp/sum + ex*V accumulate ----
    float sum = 0.f;
    float4 macc = make_float4(0.f, 0.f, 0.f, 0.f);
    {
        int sN = 0; float scC = 0.f, scN = 0.f;
        float4 v0 = make_float4(0.f, 0.f, 0.f, 0.f);
        if (beg < end) {
            int s0 = srcs[beg];
            scC = scbuf[(size_t)beg * 4 + h];
            v0 = *(const float4*)(V + (size_t)s0 * 256 + lane * 4);
        }
        if (beg + 1 < end) { sN = srcs[beg + 1]; scN = scbuf[(size_t)(beg + 1) * 4 + h]; }
        for (int j = beg; j < end; ++j) {
            int sNN = 0; float scNN = 0.f;
            if (j + 2 < end) { sNN = srcs[j + 2]; scNN = scbuf[(size_t)(j + 2) * 4 + h]; }
            float4 v1 = v0;
            if (j + 1 < end) v1 = *(const float4*)(V + (size_t)sN * 256 + lane * 4);
            float ex = expf(scC - mx);
            sum += ex;
            macc.x += ex * v0.x; macc.y += ex * v0.y;
            macc.z += ex * v0.z; macc.w += ex * v0.w;
            v0 = v1; scC = scN; sN = sNN; scN = scNN;
        }
    }
    float inv = 1.f / (sum + 1e-10f);
    float vals[4] = {macc.x * inv, macc.y * inv, macc.z * inv, macc.w * inv};
    unsigned short hs[4], ls[4];
    #pragma unroll
    for (int i = 0; i < 4; ++i) {
        __bf16 hh = (__bf16)vals[i];
        hs[i] = __builtin_bit_cast(unsigned short, hh);
        ls[i] = __builtin_bit_cast(unsigned short, (__bf16)(vals[i] - (float)hh));
    }
    // packed slot: cols c = 4*lane..4*lane+3 of row t
    size_t base = (((size_t)(t >> 5) * 16 + (lane >> 2)) * 64 + ((lane >> 1) & 1) * 32 + (t & 31)) * 8
                + ((lane & 1) << 2);
    *(ushort4*)(msgH + base) = make_ushort4(hs[0], hs[1], hs[2], hs[3]);
    *(ushort4*)(msgL + base) = make_ushort4(ls[0], ls[1], ls[2], ls[3]);
}

// ================= packed-operand MFMA bf16x3 GEMM, depth-2 counted-vmcnt =================
// C = act(A @ W + bias). Block = 64 rows x 256 cols (full N -> A staged ONCE).
// 4 waves; wave w owns cols [w*64, w*64+64) x all 64 rows = 2x2 subtiles of 32x32.
// A hi/lo staged via global_load_lds into 3 LDS buffers (BK=64, 16 KB/stage, 48 KB);
// stage st+2 issued each iteration; top-of-iter wait = s_waitcnt vmcnt(20)
// (16 B-loads + 4 staging issued per iter, asm-fenced) + raw s_barrier — never
// drains in-flight prefetch (the m201 wait-then-barrier pattern). B fragments are
// loaded to registers BEFORE issuing staging so their waits can't drain the pipe.
template<int CONCAT, int PACKOUT>
__global__ __launch_bounds__(256, 2) void gemm_pk(
    const unsigned short* __restrict__ Ah, const unsigned short* __restrict__ Al,
    const unsigned short* __restrict__ A2h, const unsigned short* __restrict__ A2l,
    const unsigned short* __restrict__ Bh, const unsigned short* __restrict__ Bl,
    const float* __restrict__ bias, int act, int M,
    float* __restrict__ Cf, unsigned short* __restrict__ Ch, unsigned short* __restrict__ Cl)
{
    const int KB = CONCAT ? 32 : 16;     // B k-blocks
    const int NS = CONCAT ? 8 : 4;       // stages (BK=64 -> 4 kb-steps each)
    const int RB = (M + 31) >> 5;
    const int lane = threadIdx.x & 63;
    const int w = threadIdx.x >> 6;
    const int rbb = blockIdx.x * 2;
    const int nb0 = w * 2;

    __shared__ union {
        unsigned short stage[3][2][2][4][512];  // [buf][half][rb][kb][lane*8] = 48 KB
        float tbuf[4][32 * 33];
    } sm __attribute__((aligned(16)));

    f32x16 acc[2][2] = {};   // [rb][nt]

    // staging unit u (0..15): half=u>>3, rb=(u>>2)&1, kb=u&3; wave w issues u=w*4..w*4+3
    auto stage_one = [&](int bufn, int st, int u) {
        int half = u >> 3, rb = (u >> 2) & 1, kb = u & 3;
        int kbg = st * 4 + kb;
        const unsigned short* srcp;
        int kba = kbg;
        if (CONCAT && kbg >= 16) { kba = kbg - 16; srcp = half ? A2l : A2h; }
        else                     { srcp = half ? Al : Ah; }
        int rbl = min(rbb + rb, RB - 1);
        const unsigned short* g = srcp + ((size_t)(rbl * 16 + kba) * 64 + lane) * 8;
        gload_lds16(g, &sm.stage[bufn][half][rb][kb][0]);
    };

    // prologue: stages 0,1 (4 loads each per wave); wait stage 0, keep stage 1 flying
    #pragma unroll
    for (int i = 0; i < 4; ++i) stage_one(0, 0, w * 4 + i);
    #pragma unroll
    for (int i = 0; i < 4; ++i) stage_one(1, 1, w * 4 + i);
    asm volatile("s_waitcnt vmcnt(4)" ::: "memory");
    __builtin_amdgcn_s_barrier();

    for (int st = 0; st < NS; ++st) {
        if (st) {
            // stage st resident check: exactly 20 VMEM (16 B + 4 staging) issued per
            // iteration after stage st's loads -> vmcnt(20) waits precisely for them.
            asm volatile("s_waitcnt vmcnt(20)" ::: "memory");
            __builtin_amdgcn_s_barrier();
        }
        const int buf = st % 3;

        // ---- B fragments for this stage -> registers (issued BEFORE staging) ----
        ushort8 Breg[4][4];
        #pragma unroll
        for (int kb = 0; kb < 4; ++kb) {
            int kbg = st * 4 + kb;
            size_t t0 = ((size_t)((nb0 + 0) * KB + kbg) * 64 + lane) * 8;
            size_t t1 = ((size_t)((nb0 + 1) * KB + kbg) * 64 + lane) * 8;
            Breg[kb][0] = *(const ushort8*)(Bh + t0);
            Breg[kb][1] = *(const ushort8*)(Bl + t0);
            Breg[kb][2] = *(const ushort8*)(Bh + t1);
            Breg[kb][3] = *(const ushort8*)(Bl + t1);
        }

        // ---- issue stage st+2 into the free buffer ----
        {
            int bufn = (st + 2) % 3;
            int stc = (st + 2 < NS) ? (st + 2) : (NS - 1);  // tail: harmless reload
            #pragma unroll
            for (int i = 0; i < 4; ++i) stage_one(bufn, stc, w * 4 + i);
        }

        // ---- compute stage st ----
        #pragma unroll
        for (int kb = 0; kb < 4; ++kb) {
            bf16x8 a0h = __builtin_bit_cast(bf16x8, *(const ushort8*)&sm.stage[buf][0][0][kb][lane * 8]);
            bf16x8 a0l = __builtin_bit_cast(bf16x8, *(const ushort8*)&sm.stage[buf][1][0][kb][lane * 8]);
            bf16x8 a1h = __builtin_bit_cast(bf16x8, *(const ushort8*)&sm.stage[buf][0][1][kb][lane * 8]);
            bf16x8 a1l = __builtin_bit_cast(bf16x8, *(const ushort8*)&sm.stage[buf][1][1][kb][lane * 8]);
            bf16x8 b0h = __builtin_bit_cast(bf16x8, Breg[kb][0]);
            bf16x8 b0l = __builtin_bit_cast(bf16x8, Breg[kb][1]);
            bf16x8 b1h = __builtin_bit_cast(bf16x8, Breg[kb][2]);
            bf16x8 b1l = __builtin_bit_cast(bf16x8, Breg[kb][3]);
            acc[0][0] = __builtin_amdgcn_mfma_f32_32x32x16_bf16(a0h, b0h, acc[0][0], 0, 0, 0);
            acc[0][0] = __builtin_amdgcn_mfma_f32_32x32x16_bf16(a0h, b0l, acc[0][0], 0, 0, 0);
            acc[0][0] = __builtin_amdgcn_mfma_f32_32x32x16_bf16(a0l, b0h, acc[0][0], 0, 0, 0);
            acc[0][1] = __builtin_amdgcn_mfma_f32_32x32x16_bf16(a0h, b1h, acc[0][1], 0, 0, 0);
            acc[0][1] = __builtin_amdgcn_mfma_f32_32x32x16_bf16(a0h, b1l, acc[0][1], 0, 0, 0);
            acc[0][1] = __builtin_amdgcn_mfma_f32_32x32x16_bf16(a0l, b1h, acc[0][1], 0, 0, 0);
            acc[1][0] = __builtin_amdgcn_mfma_f32_32x32x16_bf16(a1h, b0h, acc[1][0], 0, 0, 0);
            acc[1][0] = __builtin_amdgcn_mfma_f32_32x32x16_bf16(a1h, b0l, acc[1][0], 0, 0, 0);
            acc[1][0] = __builtin_amdgcn_mfma_f32_32x32x16_bf16(a1l, b0h, acc[1][0], 0, 0, 0);
            acc[1][1] = __builtin_amdgcn_mfma_f32_32x32x16_bf16(a1h, b1h, acc[1][1], 0, 0, 0);
            acc[1][1] = __builtin_amdgcn_mfma_f32_32x32x16_bf16(a1h, b1l, acc[1][1], 0, 0, 0);
            acc[1][1] = __builtin_amdgcn_mfma_f32_32x32x16_bf16(a1l, b1h, acc[1][1], 0, 0, 0);
        }
    }

    // drain stray prefetches before re-using the LDS union
    asm volatile("s_waitcnt vmcnt(0)" ::: "memory");
    __builtin_amdgcn_s_barrier();

    // ---- epilogue: bias + act, per-wave LDS transpose, coalesced stores ----
    const int m2 = lane & 31;
    #pragma unroll
    for (int mt = 0; mt < 2; ++mt) {
        int rb = rbb + mt;
        bool rvalid = rb < RB;
        int mg = rb * 32 + m2;
        #pragma unroll
        for (int nt = 0; nt < 2; ++nt) {
            int nb = nb0 + nt;
            float bv = bias ? bias[nb * 32 + (lane & 31)] : 0.f;
            #pragma unroll
            for (int r = 0; r < 16; ++r) {
                int ml = (r & 3) + ((r >> 2) << 3) + ((lane >> 5) << 2);
                float v = acc[mt][nt][r] + bv;
                if (act) v = gelu_exact(v);
                sm.tbuf[w][ml * 33 + (lane & 31)] = v;
            }
            asm volatile("s_waitcnt lgkmcnt(0)" ::: "memory");
            #pragma unroll
            for (int qq = 0; qq < 2; ++qq) {
                int c0 = ((lane >> 5) << 3) + (qq << 4);   // 0,8,16,24 local col
                float vs[8];
                #pragma unroll
                for (int i = 0; i < 8; ++i) vs[i] = sm.tbuf[w][m2 * 33 + c0 + i];
                if (PACKOUT) {
                    ushort8 hh, ll;
                    #pragma unroll
                    for (int i = 0; i < 8; ++i) {
                        __bf16 hb = (__bf16)vs[i];
                        hh[i] = __builtin_bit_cast(unsigned short, hb);
                        ll[i] = __builtin_bit_cast(unsigned short, (__bf16)(vs[i] - (float)hb));
                    }
                    int ng = nb * 32 + c0;
                    size_t slot = (((size_t)rb * 16 + (ng >> 4)) * 64 + ((ng >> 3) & 1) * 32 + m2) * 8;
                    if (rvalid) {
                        *(ushort8*)(Ch + slot) = hh;
                        *(ushort8*)(Cl + slot) = ll;
                    }
                } else {
                    if (mg < M) {
                        float* cp = Cf + (size_t)mg * 256 + nb * 32 + c0;
                        *(float4*)(cp)     = make_float4(vs[0], vs[1], vs[2], vs[3]);
                        *(float4*)(cp + 4) = make_float4(vs[4], vs[5], vs[6], vs[7]);
                    }
                }
            }
            asm volatile("s_waitcnt lgkmcnt(0)" ::: "memory");  // tbuf reuse safe (same wave)
        }
    }
}

// ================= host =================
extern "C" void kernel_launch(void* const* d_in, const int* in_sizes, int n_in,
                              void* d_out, int out_size, void* d_ws, size_t ws_size,
                              hipStream_t stream) {
    const float* inv_h    = (const float*)d_in[0];
    const float* asset_h  = (const float*)d_in[1];
    const float* inv_nw   = (const float*)d_in[2];
    const float* asset_nw = (const float*)d_in[3];
    const float* m_w1 = (const float*)d_in[4];
    const float* m_b1 = (const float*)d_in[5];
    const float* m_w2 = (const float*)d_in[6];
    const float* m_b2 = (const float*)d_in[7];
    const float* Wq   = (const float*)d_in[8];
    const float* Wk   = (const float*)d_in[9];
    const float* Wv   = (const float*)d_in[10];
    const float* u_w1 = (const float*)d_in[11];
    const float* u_b1 = (const float*)d_in[12];
    const float* u_w2 = (const float*)d_in[13];
    const float* u_b2 = (const float*)d_in[14];
    const int* etgt  = (const int*)d_in[15];
    const int* esrc  = (const int*)d_in[16];

    const int I = in_sizes[0] / 256;
    const int A = in_sizes[1] / 256;
    const int E = in_sizes[15];
    const int RBI = (I + 31) >> 5;
    const int RBA = (A + 31) >> 5;

    float* out_inv   = (float*)d_out;
    float* out_asset = (float*)d_out + (size_t)I * 256;

    char* wsp = (char*)d_ws;
    size_t off = 0;
    auto alloc = [&](size_t bytes) -> char* {
        char* p = wsp + off;
        off += (bytes + 255) & ~(size_t)255;
        return p;
    };

    const size_t ipackHalf = (size_t)RBI * 16384;  // bytes per half (hi or lo)
    const size_t apackHalf = (size_t)RBA * 16384;
    const size_t if32 = (size_t)I * 1024;
    const size_t af32 = (size_t)A * 1024;
    const size_t r_sz = (2 * ipackHalf > if32) ? 2 * ipackHalf : if32;
    const size_t s_sz = (2 * apackHalf > af32) ? 2 * apackHalf : af32;

    unsigned short* invP_h  = (unsigned short*)alloc(ipackHalf);
    unsigned short* invP_l  = (unsigned short*)alloc(ipackHalf);
    unsigned short* astP_h  = (unsigned short*)alloc(apackHalf);
    unsigned short* astP_l  = (unsigned short*)alloc(apackHalf);
    char* R1 = alloc(r_sz);   // tP_i pack | V_i f32 | Q_i f32 | hidP_i pack
    char* R2 = alloc(r_sz);   // MP_i pack | K_i f32 | msgP_i pack
    char* S1 = alloc(s_sz);   // Q_a f32 | tP_a pack | V_a f32
    char* S2 = alloc(s_sz);   // msgP_a pack | MP_a pack | K_a f32
    char* S3 = alloc(s_sz);   // hidP_a pack
    float* scbuf = (float*)alloc((size_t)E * 4 * 4);
    int* cnt_i  = (int*)alloc((size_t)I * 4);
    int* cnt_a  = (int*)alloc((size_t)A * 4);
    int* offs_i = (int*)alloc((size_t)(I + 1) * 4);
    int* offs_a = (int*)alloc((size_t)(A + 1) * 4);
    int* gsrc_i = (int*)alloc((size_t)E * 4);
    int* gsrc_a = (int*)alloc((size_t)E * 4);
    float* glw_i = (float*)alloc((size_t)E * 4);
    float* glw_a = (float*)alloc((size_t)E * 4);
    int* bsum_i = (int*)alloc(256 * 4);
    int* bsum_a = (int*)alloc(256 * 4);

    // weight packs
    PrepArgs pa;
    const float* wsrc[7] = {m_w1, m_w2, Wq, Wk, Wv, u_w1, u_w2};
    const int    wK[7]   = {256, 256, 256, 256, 256, 512, 256};
    unsigned short* wph[7];
    unsigned short* wpl[7];
    pa.off[0] = 0;
    for (int i = 0; i < 7; ++i) {
        size_t slots = (size_t)(wK[i] >> 4) * 8 * 64;
        wph[i] = (unsigned short*)alloc(slots * 16);
        wpl[i] = (unsigned short*)alloc(slots * 16);
        pa.src[i] = wsrc[i];
        pa.hi[i] = wph[i];
        pa.lo[i] = wpl[i];
        pa.K[i] = wK[i];
        pa.off[i + 1] = pa.off[i] + (int)slots;
    }

    const int nbI = (I + 255) / 256;
    const int nbA = (A + 255) / 256;
    const int nbE = (E + 255) / 256;

    // ---- operand prep ----
    hipLaunchKernelGGL(prep_w, dim3((pa.off[7] + 255) / 256), dim3(256), 0, stream, pa);
    hipLaunchKernelGGL(pack_rows, dim3((RBI * 1024 + 255) / 256), dim3(256), 0, stream,
                       inv_h, invP_h, invP_l, I, RBI);
    hipLaunchKernelGGL(pack_rows, dim3((RBA * 1024 + 255) / 256), dim3(256), 0, stream,
                       asset_h, astP_h, astP_l, A, RBA);

    // ---- CSR build ----
    hipMemsetAsync(cnt_i, 0, (size_t)I * 4, stream);
    hipMemsetAsync(cnt_a, 0, (size_t)A * 4, stream);
    hipLaunchKernelGGL(count_kernel, dim3(nbE), dim3(256), 0, stream,
                       etgt, esrc, cnt_i, cnt_a, E);
    hipLaunchKernelGGL(scan_block, dim3(nbI), dim3(256), 0, stream, cnt_i, offs_i, bsum_i, I);
    hipLaunchKernelGGL(scan_block, dim3(nbA), dim3(256), 0, stream, cnt_a, offs_a, bsum_a, A);
    hipLaunchKernelGGL(scan_bsum, dim3(1), dim3(256), 0, stream, bsum_i, nbI);
    hipLaunchKernelGGL(scan_bsum, dim3(1), dim3(256), 0, stream, bsum_a, nbA);
    hipLaunchKernelGGL(add_offs, dim3(nbI), dim3(256), 0, stream, offs_i, cnt_i, bsum_i, I, E);
    hipLaunchKernelGGL(add_offs, dim3(nbA), dim3(256), 0, stream, offs_a, cnt_a, bsum_a, A, E);
    hipLaunchKernelGGL(fill_kernel, dim3(nbE), dim3(256), 0, stream,
                       etgt, esrc, inv_nw, asset_nw, cnt_i, cnt_a,
                       gsrc_i, glw_i, gsrc_a, glw_a, E);

    // gemm launcher. outmode: 0 = f32 Cf, 1 = packed (cH,cL)
    auto gemm = [&](const unsigned short* aH, const unsigned short* aL,
                    const unsigned short* a2H, const unsigned short* a2L,
                    int M, int widx, const float* bias, int act,
                    float* cf, unsigned short* cH, unsigned short* cL, int concat) {
        dim3 grid((((M + 31) >> 5) + 1) / 2);
        if (concat) {
            if (cf) hipLaunchKernelGGL((gemm_pk<1,0>), grid, dim3(256), 0, stream,
                        aH, aL, a2H, a2L, wph[widx], wpl[widx], bias, act, M, cf, cH, cL);
            else    hipLaunchKernelGGL((gemm_pk<1,1>), grid, dim3(256), 0, stream,
                        aH, aL, a2H, a2L, wph[widx], wpl[widx], bias, act, M, cf, cH, cL);
        } else {
            if (cf) hipLaunchKernelGGL((gemm_pk<0,0>), grid, dim3(256), 0, stream,
                        aH, aL, a2H, a2L, wph[widx], wpl[widx], bias, act, M, cf, cH, cL);
            else    hipLaunchKernelGGL((gemm_pk<0,1>), grid, dim3(256), 0, stream,
                        aH, aL, a2H, a2L, wph[widx], wpl[widx], bias, act, M, cf, cH, cL);
        }
    };
    // widx: 0=m_w1 1=m_w2 2=Wq 3=Wk 4=Wv 5=u_w1 6=u_w2

    auto ph = [&](char* r) { return (unsigned short*)r; };
    auto plI = [&](char* r) { return (unsigned short*)(r + ipackHalf); };
    auto plA = [&](char* r) { return (unsigned short*)(r + apackHalf); };

    // ===== direction 2: assets aggregate from investors =====
    gemm(invP_h, invP_l, 0, 0, I, 0, m_b1, 1, nullptr, ph(R1), plI(R1), 0);   // tP_i -> R1
    gemm(ph(R1), plI(R1), 0, 0, I, 1, m_b2, 1, nullptr, ph(R2), plI(R2), 0);  // MP_i -> R2
    gemm(ph(R2), plI(R2), 0, 0, I, 4, nullptr, 0, (float*)R1, 0, 0, 0);       // V_i f32 -> R1
    gemm(invP_h, invP_l, 0, 0, I, 3, nullptr, 0, (float*)R2, 0, 0, 0);        // K_i f32 -> R2
    gemm(astP_h, astP_l, 0, 0, A, 2, nullptr, 0, (float*)S1, 0, 0, 0);        // Q_a f32 -> S1

    hipLaunchKernelGGL(fused_attn, dim3((A + 3) / 4), dim3(256), 0, stream,
                       (float*)S1, (float*)R2, (float*)R1, offs_a, gsrc_a, glw_a,
                       scbuf, ph(S2), plA(S2), A);                            // msgP_a -> S2

    gemm(astP_h, astP_l, ph(S2), plA(S2), A, 5, u_b1, 1, nullptr, ph(S3), plA(S3), 1); // hidP_a -> S3
    gemm(ph(S3), plA(S3), 0, 0, A, 6, u_b2, 1, out_asset, 0, 0, 0);

    // ===== direction 1: investors aggregate from assets =====
    gemm(astP_h, astP_l, 0, 0, A, 0, m_b1, 1, nullptr, ph(S1), plA(S1), 0);   // tP_a -> S1
    gemm(ph(S1), plA(S1), 0, 0, A, 1, m_b2, 1, nullptr, ph(S2), plA(S2), 0);  // MP_a -> S2
    gemm(ph(S2), plA(S2), 0, 0, A, 4, nullptr, 0, (float*)S1, 0, 0, 0);       // V_a f32 -> S1
    gemm(astP_h, astP_l, 0, 0, A, 3, nullptr, 0, (float*)S2, 0, 0, 0);        // K_a f32 -> S2
    gemm(invP_h, invP_l, 0, 0, I, 2, nullptr, 0, (float*)R1, 0, 0, 0);        // Q_i f32 -> R1

    hipLaunchKernelGGL(fused_attn, dim3((I + 3) / 4), dim3(256), 0, stream,
                       (float*)R1, (float*)S2, (float*)S1, offs_i, gsrc_i, glw_i,
                       scbuf, ph(R2), plI(R2), I);                            // msgP_i -> R2

    gemm(invP_h, invP_l, ph(R2), plI(R2), I, 5, u_b1, 1, nullptr, ph(R1), plI(R1), 1); // hidP_i -> R1
    gemm(ph(R1), plI(R1), 0, 0, I, 6, u_b2, 1, out_inv, 0, 0, 0);
}

// Round 6
// 701.007 us; speedup vs baseline: 1.8791x; 1.1924x over previous
//
#include <hip/hip_runtime.h>

typedef __bf16 bf16x8 __attribute__((ext_vector_type(8)));
typedef float f32x16 __attribute__((ext_vector_type(16)));
typedef unsigned short ushort8 __attribute__((ext_vector_type(8)));

// ---------- helpers ----------
__device__ __forceinline__ float gelu_exact(float x) {
    return 0.5f * x * (1.0f + erff(x * 0.70710678118654752440f));
}

// async global->LDS, 16B per lane; dest is wave-uniform base, HW adds lane*16
__device__ __forceinline__ void gload_lds16(const void* g, void* l) {
    __builtin_amdgcn_global_load_lds(
        (const __attribute__((address_space(1))) unsigned int*)g,
        (__attribute__((address_space(3))) unsigned int*)l, 16, 0, 0);
}

#define MFMA(a, b, c) __builtin_amdgcn_mfma_f32_32x32x16_bf16((a), (b), (c), 0, 0, 0)

// =====================================================================
// Packed operand layout (bf16 hi/lo, MFMA-fragment-linear):
//   A-pack for [M][256]: slot s = (rb*16 + kb)*64 + lane, 8 ushorts each.
//     lane's elems = A[rb*32 + (lane&31)][kb*16 + (lane>>5)*8 + i], i=0..7
//   B-pack for W[K][256]: slot = (nb*KB + kb)*64 + lane, KB = K/16.
//     lane's elems = W[kb*16 + (lane>>5)*8 + i][nb*32 + (lane&31)]
//   LDS A/pack region (32 rows x 256 k, hi/lo): byte off =
//     hl*16384 + kb*1024 + lane*16   (lane = khalf*32 + m; elem i at +2i)
// =====================================================================

// ================= CSR build =================
__global__ __launch_bounds__(256) void count_kernel(
    const int* __restrict__ tgt, const int* __restrict__ src,
    int* __restrict__ cnt_i, int* __restrict__ cnt_a, int E)
{
    int e = blockIdx.x * 256 + threadIdx.x;
    if (e < E) {
        atomicAdd(&cnt_i[tgt[e]], 1);
        atomicAdd(&cnt_a[src[e]], 1);
    }
}

__global__ __launch_bounds__(256) void scan_block(
    const int* __restrict__ cnt, int* __restrict__ offs, int* __restrict__ bsum, int N)
{
    __shared__ int s[256];
    int i = blockIdx.x * 256 + threadIdx.x;
    int v = (i < N) ? cnt[i] : 0;
    s[threadIdx.x] = v;
    __syncthreads();
    for (int d = 1; d < 256; d <<= 1) {
        int t = (threadIdx.x >= d) ? s[threadIdx.x - d] : 0;
        __syncthreads();
        s[threadIdx.x] += t;
        __syncthreads();
    }
    if (i < N) offs[i] = s[threadIdx.x] - v;   // exclusive
    if (threadIdx.x == 255) bsum[blockIdx.x] = s[255];
}

__global__ __launch_bounds__(256) void scan_bsum(int* __restrict__ bsum, int nb)
{
    __shared__ int s[256];
    int v = (threadIdx.x < nb) ? bsum[threadIdx.x] : 0;
    s[threadIdx.x] = v;
    __syncthreads();
    for (int d = 1; d < 256; d <<= 1) {
        int t = (threadIdx.x >= d) ? s[threadIdx.x - d] : 0;
        __syncthreads();
        s[threadIdx.x] += t;
        __syncthreads();
    }
    if (threadIdx.x < nb) bsum[threadIdx.x] = s[threadIdx.x] - v;  // exclusive
}

__global__ __launch_bounds__(256) void add_offs(
    int* __restrict__ offs, int* __restrict__ cursor,
    const int* __restrict__ bsum, int N, int E)
{
    int i = blockIdx.x * 256 + threadIdx.x;
    if (i < N) {
        int f = offs[i] + bsum[blockIdx.x];
        offs[i] = f;
        cursor[i] = f;
    }
    if (i == 0) offs[N] = E;
}

// materialize CSR-ordered source index + log(nw)
__global__ __launch_bounds__(256) void fill_kernel(
    const int* __restrict__ tgt, const int* __restrict__ src,
    const float* __restrict__ nw_i, const float* __restrict__ nw_a,
    int* __restrict__ cur_i, int* __restrict__ cur_a,
    int* __restrict__ src_i, float* __restrict__ lw_i,
    int* __restrict__ src_a, float* __restrict__ lw_a, int E)
{
    int e = blockIdx.x * 256 + threadIdx.x;
    if (e < E) {
        int t = tgt[e], s = src[e];
        float li = logf(fmaxf(nw_i[e], 1e-10f));
        float la = logf(fmaxf(nw_a[e], 1e-10f));
        int p = atomicAdd(&cur_i[t], 1);
        src_i[p] = s; lw_i[p] = li;
        int q = atomicAdd(&cur_a[s], 1);
        src_a[q] = t; lw_a[q] = la;
    }
}

// ================= weight prep: f32 W[K][256] -> packed B fragments =================
struct PrepArgs {
    const float* src[7];
    unsigned short* hi[7];
    unsigned short* lo[7];
    int K[7];
    int off[8];   // slot offsets; slots per matrix = (K/16)*8*64
};

__global__ __launch_bounds__(256) void prep_w(PrepArgs a)
{
    int s = blockIdx.x * 256 + threadIdx.x;
    if (s >= a.off[7]) return;
    int m = 0;
    #pragma unroll
    for (int i = 0; i < 6; ++i) m += (s >= a.off[i + 1]) ? 1 : 0;
    int sl = s - a.off[m];
    int KB = a.K[m] >> 4;
    int l  = sl & 63;
    int kb = (sl >> 6) % KB;
    int nb = (sl >> 6) / KB;
    int n  = nb * 32 + (l & 31);
    int k0 = kb * 16 + ((l >> 5) << 3);
    ushort8 hh, ll;
    #pragma unroll
    for (int i = 0; i < 8; ++i) {
        float x = a.src[m][(size_t)(k0 + i) * 256 + n];
        __bf16 h = (__bf16)x;
        hh[i] = __builtin_bit_cast(unsigned short, h);
        ll[i] = __builtin_bit_cast(unsigned short, (__bf16)(x - (float)h));
    }
    *(ushort8*)(a.hi[m] + (size_t)sl * 8) = hh;
    *(ushort8*)(a.lo[m] + (size_t)sl * 8) = ll;
}

// ================= row pack: f32 X[M][256] -> packed A fragments =================
__global__ __launch_bounds__(256) void pack_rows(
    const float* __restrict__ X, unsigned short* __restrict__ Ph,
    unsigned short* __restrict__ Pl, int M, int RB)
{
    int s = blockIdx.x * 256 + threadIdx.x;
    int total = RB * 16 * 64;
    if (s >= total) return;
    int l  = s & 63;
    int kb = (s >> 6) & 15;
    int rb = s >> 10;
    int row = min(rb * 32 + (l & 31), M - 1);
    int k0  = kb * 16 + ((l >> 5) << 3);
    const float* p = X + (size_t)row * 256 + k0;
    float4 f0 = *(const float4*)p;
    float4 f1 = *(const float4*)(p + 4);
    float xs[8] = {f0.x, f0.y, f0.z, f0.w, f1.x, f1.y, f1.z, f1.w};
    ushort8 hh, ll;
    #pragma unroll
    for (int i = 0; i < 8; ++i) {
        __bf16 h = (__bf16)xs[i];
        hh[i] = __builtin_bit_cast(unsigned short, h);
        ll[i] = __builtin_bit_cast(unsigned short, (__bf16)(xs[i] - (float)h));
    }
    *(ushort8*)(Ph + (size_t)s * 8) = hh;
    *(ushort8*)(Pl + (size_t)s * 8) = ll;
}

// ================= fused per-target attention (unchanged, proven) =================
__global__ __launch_bounds__(256) void fused_attn(
    const float* __restrict__ Q, const float* __restrict__ Kk, const float* __restrict__ V,
    const int* __restrict__ offs, const int* __restrict__ srcs,
    const float* __restrict__ lws,
    float* __restrict__ scbuf, unsigned short* __restrict__ msgH,
    unsigned short* __restrict__ msgL, int T)
{
    int w = blockIdx.x * 4 + (threadIdx.x >> 6);
    int lane = threadIdx.x & 63;
    if (w >= T) return;
    int t = w;
    int beg = offs[t], end = offs[t + 1];
    int h = lane >> 4;

    float4 q = *(const float4*)(Q + (size_t)t * 256 + lane * 4);

    // ---- pass 1: scores + running max ----
    float mx = 0.f;   // 0-init matches torch scatter amax include_self with zeros
    {
        int sN = 0; float lC = 0.f, lN = 0.f;
        float4 k0 = make_float4(0.f, 0.f, 0.f, 0.f);
        if (beg < end) {
            int s0 = srcs[beg];
            lC = lws[beg];
            k0 = *(const float4*)(Kk + (size_t)s0 * 256 + lane * 4);
        }
        if (beg + 1 < end) { sN = srcs[beg + 1]; lN = lws[beg + 1]; }
        for (int j = beg; j < end; ++j) {
            int sNN = 0; float lNN = 0.f;
            if (j + 2 < end) { sNN = srcs[j + 2]; lNN = lws[j + 2]; }
            float4 k1 = k0;
            if (j + 1 < end) k1 = *(const float4*)(Kk + (size_t)sN * 256 + lane * 4);
            float d = q.x * k0.x + q.y * k0.y + q.z * k0.z + q.w * k0.w;
            d += __shfl_xor(d, 1);
            d += __shfl_xor(d, 2);
            d += __shfl_xor(d, 4);
            d += __shfl_xor(d, 8);
            float sc = d * 0.125f + lC;
            if ((lane & 15) == 0) scbuf[(size_t)j * 4 + h] = sc;
            mx = fmaxf(mx, sc);
            k0 = k1; lC = lN; sN = sNN; lN = lNN;
        }
    }

    // ---- pass 2: exp/sum + ex*V accumulate ----
    float sum = 0.f;
    float4 macc = make_float4(0.f, 0.f, 0.f, 0.f);
    {
        int sN = 0; float scC = 0.f, scN = 0.f;
        float4 v0 = make_float4(0.f, 0.f, 0.f, 0.f);
        if (beg < end) {
            int s0 = srcs[beg];
            scC = scbuf[(size_t)beg * 4 + h];
            v0 = *(const float4*)(V + (size_t)s0 * 256 + lane * 4);
        }
        if (beg + 1 < end) { sN = srcs[beg + 1]; scN = scbuf[(size_t)(beg + 1) * 4 + h]; }
        for (int j = beg; j < end; ++j) {
            int sNN = 0; float scNN = 0.f;
            if (j + 2 < end) { sNN = srcs[j + 2]; scNN = scbuf[(size_t)(j + 2) * 4 + h]; }
            float4 v1 = v0;
            if (j + 1 < end) v1 = *(const float4*)(V + (size_t)sN * 256 + lane * 4);
            float ex = expf(scC - mx);
            sum += ex;
            macc.x += ex * v0.x; macc.y += ex * v0.y;
            macc.z += ex * v0.z; macc.w += ex * v0.w;
            v0 = v1; scC = scN; sN = sNN; scN = scNN;
        }
    }
    float inv = 1.f / (sum + 1e-10f);
    float vals[4] = {macc.x * inv, macc.y * inv, macc.z * inv, macc.w * inv};
    unsigned short hs[4], ls[4];
    #pragma unroll
    for (int i = 0; i < 4; ++i) {
        __bf16 hh = (__bf16)vals[i];
        hs[i] = __builtin_bit_cast(unsigned short, hh);
        ls[i] = __builtin_bit_cast(unsigned short, (__bf16)(vals[i] - (float)hh));
    }
    // packed slot: cols c = 4*lane..4*lane+3 of row t
    size_t base = (((size_t)(t >> 5) * 16 + (lane >> 2)) * 64 + ((lane >> 1) & 1) * 32 + (t & 31)) * 8
                + ((lane & 1) << 2);
    *(ushort4*)(msgH + base) = make_ushort4(hs[0], hs[1], hs[2], hs[3]);
    *(ushort4*)(msgL + base) = make_ushort4(ls[0], ls[1], ls[2], ls[3]);
}

// ================= fused node kernel =================
// Block = 32 rows x 256 cols; 4 waves, wave w owns col-subtiles nb0=2w, 2w+1.
// MODE 0 (phase 1): stage 32-row h-pack slab ONCE into 32 KB LDS, then 5 full-K
//   loops off LDS: K->HBM, Q->HBM, t->packed-in-LDS (in place), M->packed-in-LDS,
//   V->HBM. t and M never touch HBM.
// MODE 1 (phase 2): round-5 streamed counted-vmcnt pipeline over K=512
//   (concat h|msg), acc hid; pack hid into LDS; out-loop reads pack, writes out.
// Dynamic LDS = 32 KB both modes. bf16x3 numerics identical to previous rounds.
template<int MODE>
__global__ __launch_bounds__(256, 3) void fused_node(
    const unsigned short* __restrict__ Ah, const unsigned short* __restrict__ Al,
    const unsigned short* __restrict__ A2h, const unsigned short* __restrict__ A2l,
    const unsigned short* __restrict__ B1h, const unsigned short* __restrict__ B1l,  // Wk | u_w1
    const unsigned short* __restrict__ B2h, const unsigned short* __restrict__ B2l,  // Wq | u_w2
    const unsigned short* __restrict__ B3h, const unsigned short* __restrict__ B3l,  // m_w1
    const unsigned short* __restrict__ B4h, const unsigned short* __restrict__ B4l,  // m_w2
    const unsigned short* __restrict__ B5h, const unsigned short* __restrict__ B5l,  // Wv
    const float* __restrict__ bias1, const float* __restrict__ bias2,
    int M,
    float* __restrict__ O1, float* __restrict__ O2, float* __restrict__ O3)
{
    extern __shared__ char smem[];
    unsigned short* sus = (unsigned short*)smem;
    const int lane = threadIdx.x & 63;
    const int w = threadIdx.x >> 6;
    const int nb0 = w * 2;
    const int rb = blockIdx.x;

    // full-K=256 GEMM off the LDS A/pack region (layout: hl*16K + kb*1024 + lane*16)
    auto gemm_lds = [&](const unsigned short* BH, const unsigned short* BL, int KBw,
                        f32x16& A0, f32x16& A1) {
        #pragma unroll 4
        for (int kb = 0; kb < 16; ++kb) {
            bf16x8 ah  = __builtin_bit_cast(bf16x8, *(const ushort8*)(smem + kb * 1024 + lane * 16));
            bf16x8 alo = __builtin_bit_cast(bf16x8, *(const ushort8*)(smem + 16384 + kb * 1024 + lane * 16));
            size_t t0 = ((size_t)((nb0 + 0) * KBw + kb) * 64 + lane) * 8;
            size_t t1 = ((size_t)((nb0 + 1) * KBw + kb) * 64 + lane) * 8;
            bf16x8 b0h = __builtin_bit_cast(bf16x8, *(const ushort8*)(BH + t0));
            bf16x8 b0l = __builtin_bit_cast(bf16x8, *(const ushort8*)(BL + t0));
            bf16x8 c1h = __builtin_bit_cast(bf16x8, *(const ushort8*)(BH + t1));
            bf16x8 c1l = __builtin_bit_cast(bf16x8, *(const ushort8*)(BL + t1));
            A0 = MFMA(ah, b0h, A0); A0 = MFMA(ah, b0l, A0); A0 = MFMA(alo, b0h, A0);
            A1 = MFMA(ah, c1h, A1); A1 = MFMA(ah, c1l, A1); A1 = MFMA(alo, c1h, A1);
        }
    };

    // C/D layout: col = lane&31, row = (r&3) + 8*(r>>2) + 4*(lane>>5)
    auto store_f32 = [&](const f32x16& A0, const f32x16& A1, const float* bias, int act,
                         float* Out) {
        #pragma unroll
        for (int nt = 0; nt < 2; ++nt) {
            const f32x16& a = nt ? A1 : A0;
            int n = (nb0 + nt) * 32 + (lane & 31);
            float bv = bias ? bias[n] : 0.f;
            #pragma unroll
            for (int r = 0; r < 16; ++r) {
                int row = rb * 32 + (r & 3) + ((r >> 2) << 3) + ((lane >> 5) << 2);
                if (row < M) {
                    float v = a[r] + bv;
                    if (act) v = gelu_exact(v);
                    Out[(size_t)row * 256 + n] = v;
                }
            }
        }
    };

    // bias + GELU + hi/lo split, written into the LDS A/pack region in place
    auto pack_to_lds = [&](const f32x16& A0, const f32x16& A1, const float* bias) {
        #pragma unroll
        for (int nt = 0; nt < 2; ++nt) {
            const f32x16& a = nt ? A1 : A0;
            int n = (nb0 + nt) * 32 + (lane & 31);
            float bv = bias[n];
            int ub = (n >> 4) * 512 + ((n >> 3) & 1) * 256 + (n & 7);   // ushort idx
            #pragma unroll
            for (int r = 0; r < 16; ++r) {
                int m = (r & 3) + ((r >> 2) << 3) + ((lane >> 5) << 2);
                float v = gelu_exact(a[r] + bv);
                __bf16 hb = (__bf16)v;
                sus[ub + m * 8] = __builtin_bit_cast(unsigned short, hb);
                sus[8192 + ub + m * 8] =
                    __builtin_bit_cast(unsigned short, (__bf16)(v - (float)hb));
            }
        }
    };

    if constexpr (MODE == 0) {
        // ---- one-shot stage of the 32-row h slab (32 KB) ----
        #pragma unroll
        for (int i = 0; i < 8; ++i) {
            int u = w * 8 + i, hl = u >> 4, kb = u & 15;
            const unsigned short* srcp = hl ? Al : Ah;
            const unsigned short* g = srcp + ((size_t)(rb * 16 + kb) * 64 + lane) * 8;
            gload_lds16(g, smem + hl * 16384 + kb * 1024);
        }
        asm volatile("s_waitcnt vmcnt(0)" ::: "memory");
        __builtin_amdgcn_s_barrier();

        { f32x16 a0 = {}, a1 = {}; gemm_lds(B1h, B1l, 16, a0, a1);
          store_f32(a0, a1, nullptr, 0, O1); }                    // K = h@Wk
        { f32x16 a0 = {}, a1 = {}; gemm_lds(B2h, B2l, 16, a0, a1);
          store_f32(a0, a1, nullptr, 0, O2); }                    // Q = h@Wq
        f32x16 t0 = {}, t1 = {};
        gemm_lds(B3h, B3l, 16, t0, t1);                           // t = h@m_w1
        __syncthreads();                                          // all A reads done
        pack_to_lds(t0, t1, bias1);                               // gelu(t+b1) -> LDS
        __syncthreads();
        f32x16 m0 = {}, m1 = {};
        gemm_lds(B4h, B4l, 16, m0, m1);                           // M = t@m_w2
        __syncthreads();
        pack_to_lds(m0, m1, bias2);                               // gelu(M+b2) -> LDS
        __syncthreads();
        { f32x16 a0 = {}, a1 = {}; gemm_lds(B5h, B5l, 16, a0, a1);
          store_f32(a0, a1, nullptr, 0, O3); }                    // V = M@Wv
    } else {
        // ---- phase 2: streamed hid over K=512 (counted-vmcnt, 3-buffer) ----
        auto stage_one = [&](int bufn, int st, int u) {
            int hl = u >> 2, kb = u & 3;
            int kbg = st * 4 + kb;
            const unsigned short* srcp; int kba = kbg;
            if (kbg >= 16) { kba = kbg - 16; srcp = hl ? A2l : A2h; }
            else           { srcp = hl ? Al : Ah; }
            const unsigned short* g = srcp + ((size_t)(rb * 16 + kba) * 64 + lane) * 8;
            gload_lds16(g, smem + bufn * 8192 + (hl * 4 + kb) * 1024);
        };
        stage_one(0, 0, w * 2); stage_one(0, 0, w * 2 + 1);
        stage_one(1, 1, w * 2); stage_one(1, 1, w * 2 + 1);
        asm volatile("s_waitcnt vmcnt(2)" ::: "memory");
        __builtin_amdgcn_s_barrier();

        f32x16 h0 = {}, h1 = {};
        for (int st = 0; st < 8; ++st) {
            if (st) {
                // per iter: 16 B-loads + 2 staging = 18 newer than stage st's loads
                asm volatile("s_waitcnt vmcnt(18)" ::: "memory");
                __builtin_amdgcn_s_barrier();
            }
            const int buf = st % 3;
            ushort8 Breg[4][4];
            #pragma unroll
            for (int kb = 0; kb < 4; ++kb) {
                int kbg = st * 4 + kb;
                size_t t0 = ((size_t)((nb0 + 0) * 32 + kbg) * 64 + lane) * 8;
                size_t t1 = ((size_t)((nb0 + 1) * 32 + kbg) * 64 + lane) * 8;
                Breg[kb][0] = *(const ushort8*)(B1h + t0);
                Breg[kb][1] = *(const ushort8*)(B1l + t0);
                Breg[kb][2] = *(const ushort8*)(B1h + t1);
                Breg[kb][3] = *(const ushort8*)(B1l + t1);
            }
            {
                int bufn = (st + 2) % 3;
                int stc = (st + 2 < 8) ? (st + 2) : 7;   // tail: harmless reload
                stage_one(bufn, stc, w * 2);
                stage_one(bufn, stc, w * 2 + 1);
            }
            #pragma unroll
            for (int kb = 0; kb < 4; ++kb) {
                bf16x8 ah  = __builtin_bit_cast(bf16x8,
                    *(const ushort8*)(smem + buf * 8192 + kb * 1024 + lane * 16));
                bf16x8 alo = __builtin_bit_cast(bf16x8,
                    *(const ushort8*)(smem + buf * 8192 + (4 + kb) * 1024 + lane * 16));
                bf16x8 b0h = __builtin_bit_cast(bf16x8, Breg[kb][0]);
                bf16x8 b0l = __builtin_bit_cast(bf16x8, Breg[kb][1]);
                bf16x8 c1h = __builtin_bit_cast(bf16x8, Breg[kb][2]);
                bf16x8 c1l = __builtin_bit_cast(bf16x8, Breg[kb][3]);
                h0 = MFMA(ah, b0h, h0); h0 = MFMA(ah, b0l, h0); h0 = MFMA(alo, b0h, h0);
                h1 = MFMA(ah, c1h, h1); h1 = MFMA(ah, c1l, h1); h1 = MFMA(alo, c1h, h1);
            }
        }
        asm volatile("s_waitcnt vmcnt(0)" ::: "memory");   // drain stray prefetches
        __builtin_amdgcn_s_barrier();

        pack_to_lds(h0, h1, bias1);                        // gelu(hid+u_b1) -> LDS
        __syncthreads();
        { f32x16 o0 = {}, o1 = {}; gemm_lds(B2h, B2l, 16, o0, o1);
          store_f32(o0, o1, bias2, 1, O3); }               // out = gelu(hid@u_w2+u_b2)
    }
}

// ================= host =================
extern "C" void kernel_launch(void* const* d_in, const int* in_sizes, int n_in,
                              void* d_out, int out_size, void* d_ws, size_t ws_size,
                              hipStream_t stream) {
    const float* inv_h    = (const float*)d_in[0];
    const float* asset_h  = (const float*)d_in[1];
    const float* inv_nw   = (const float*)d_in[2];
    const float* asset_nw = (const float*)d_in[3];
    const float* m_w1 = (const float*)d_in[4];
    const float* m_b1 = (const float*)d_in[5];
    const float* m_w2 = (const float*)d_in[6];
    const float* m_b2 = (const float*)d_in[7];
    const float* Wq   = (const float*)d_in[8];
    const float* Wk   = (const float*)d_in[9];
    const float* Wv   = (const float*)d_in[10];
    const float* u_w1 = (const float*)d_in[11];
    const float* u_b1 = (const float*)d_in[12];
    const float* u_w2 = (const float*)d_in[13];
    const float* u_b2 = (const float*)d_in[14];
    const int* etgt  = (const int*)d_in[15];
    const int* esrc  = (const int*)d_in[16];

    const int I = in_sizes[0] / 256;
    const int A = in_sizes[1] / 256;
    const int E = in_sizes[15];
    const int RBI = (I + 31) >> 5;
    const int RBA = (A + 31) >> 5;

    float* out_inv   = (float*)d_out;
    float* out_asset = (float*)d_out + (size_t)I * 256;

    char* wsp = (char*)d_ws;
    size_t off = 0;
    auto alloc = [&](size_t bytes) -> char* {
        char* p = wsp + off;
        off += (bytes + 255) & ~(size_t)255;
        return p;
    };

    const size_t ipackHalf = (size_t)RBI * 16384;  // bytes per half (hi or lo)
    const size_t apackHalf = (size_t)RBA * 16384;

    unsigned short* invP_h = (unsigned short*)alloc(ipackHalf);
    unsigned short* invP_l = (unsigned short*)alloc(ipackHalf);
    unsigned short* astP_h = (unsigned short*)alloc(apackHalf);
    unsigned short* astP_l = (unsigned short*)alloc(apackHalf);
    // K_i f32; later overlaid by msgP_i (K_i dead after dir-2 attn)
    char* KfI_raw = alloc(2 * ipackHalf);
    float* KfI = (float*)KfI_raw;
    unsigned short* msgI_h = (unsigned short*)KfI_raw;
    unsigned short* msgI_l = (unsigned short*)(KfI_raw + ipackHalf);
    float* QfI = (float*)alloc((size_t)I * 1024);
    float* VfI = (float*)alloc((size_t)I * 1024);
    float* KfA = (float*)alloc((size_t)A * 1024);
    float* QfA = (float*)alloc((size_t)A * 1024);
    float* VfA = (float*)alloc((size_t)A * 1024);
    unsigned short* msgA_h = (unsigned short*)alloc(apackHalf);
    unsigned short* msgA_l = (unsigned short*)alloc(apackHalf);
    float* scbuf = (float*)alloc((size_t)E * 4 * 4);
    int* cnt_i  = (int*)alloc((size_t)I * 4);
    int* cnt_a  = (int*)alloc((size_t)A * 4);
    int* offs_i = (int*)alloc((size_t)(I + 1) * 4);
    int* offs_a = (int*)alloc((size_t)(A + 1) * 4);
    int* gsrc_i = (int*)alloc((size_t)E * 4);
    int* gsrc_a = (int*)alloc((size_t)E * 4);
    float* glw_i = (float*)alloc((size_t)E * 4);
    float* glw_a = (float*)alloc((size_t)E * 4);
    int* bsum_i = (int*)alloc(256 * 4);
    int* bsum_a = (int*)alloc(256 * 4);

    // weight packs: 0=m_w1 1=m_w2 2=Wq 3=Wk 4=Wv 5=u_w1 6=u_w2
    PrepArgs pa;
    const float* wsrc[7] = {m_w1, m_w2, Wq, Wk, Wv, u_w1, u_w2};
    const int    wK[7]   = {256, 256, 256, 256, 256, 512, 256};
    unsigned short* wph[7];
    unsigned short* wpl[7];
    pa.off[0] = 0;
    for (int i = 0; i < 7; ++i) {
        size_t slots = (size_t)(wK[i] >> 4) * 8 * 64;
        wph[i] = (unsigned short*)alloc(slots * 16);
        wpl[i] = (unsigned short*)alloc(slots * 16);
        pa.src[i] = wsrc[i];
        pa.hi[i] = wph[i];
        pa.lo[i] = wpl[i];
        pa.K[i] = wK[i];
        pa.off[i + 1] = pa.off[i] + (int)slots;
    }

    const int nbI = (I + 255) / 256;
    const int nbA = (A + 255) / 256;
    const int nbE = (E + 255) / 256;

    // ---- operand prep ----
    hipLaunchKernelGGL(prep_w, dim3((pa.off[7] + 255) / 256), dim3(256), 0, stream, pa);
    hipLaunchKernelGGL(pack_rows, dim3((RBI * 1024 + 255) / 256), dim3(256), 0, stream,
                       inv_h, invP_h, invP_l, I, RBI);
    hipLaunchKernelGGL(pack_rows, dim3((RBA * 1024 + 255) / 256), dim3(256), 0, stream,
                       asset_h, astP_h, astP_l, A, RBA);

    // ---- CSR build ----
    hipMemsetAsync(cnt_i, 0, (size_t)I * 4, stream);
    hipMemsetAsync(cnt_a, 0, (size_t)A * 4, stream);
    hipLaunchKernelGGL(count_kernel, dim3(nbE), dim3(256), 0, stream,
                       etgt, esrc, cnt_i, cnt_a, E);
    hipLaunchKernelGGL(scan_block, dim3(nbI), dim3(256), 0, stream, cnt_i, offs_i, bsum_i, I);
    hipLaunchKernelGGL(scan_block, dim3(nbA), dim3(256), 0, stream, cnt_a, offs_a, bsum_a, A);
    hipLaunchKernelGGL(scan_bsum, dim3(1), dim3(256), 0, stream, bsum_i, nbI);
    hipLaunchKernelGGL(scan_bsum, dim3(1), dim3(256), 0, stream, bsum_a, nbA);
    hipLaunchKernelGGL(add_offs, dim3(nbI), dim3(256), 0, stream, offs_i, cnt_i, bsum_i, I, E);
    hipLaunchKernelGGL(add_offs, dim3(nbA), dim3(256), 0, stream, offs_a, cnt_a, bsum_a, A, E);
    hipLaunchKernelGGL(fill_kernel, dim3(nbE), dim3(256), 0, stream,
                       etgt, esrc, inv_nw, asset_nw, cnt_i, cnt_a,
                       gsrc_i, glw_i, gsrc_a, glw_a, E);

    // ---- phase 1: per node type, fused K/Q/t/M/V ----
    hipLaunchKernelGGL((fused_node<0>), dim3(RBI), dim3(256), 32768, stream,
                       invP_h, invP_l, (const unsigned short*)nullptr, (const unsigned short*)nullptr,
                       wph[3], wpl[3],  // Wk
                       wph[2], wpl[2],  // Wq
                       wph[0], wpl[0],  // m_w1
                       wph[1], wpl[1],  // m_w2
                       wph[4], wpl[4],  // Wv
                       m_b1, m_b2, I, KfI, QfI, VfI);
    hipLaunchKernelGGL((fused_node<0>), dim3(RBA), dim3(256), 32768, stream,
                       astP_h, astP_l, (const unsigned short*)nullptr, (const unsigned short*)nullptr,
                       wph[3], wpl[3], wph[2], wpl[2], wph[0], wpl[0],
                       wph[1], wpl[1], wph[4], wpl[4],
                       m_b1, m_b2, A, KfA, QfA, VfA);

    // ---- attention ----
    hipLaunchKernelGGL(fused_attn, dim3((A + 3) / 4), dim3(256), 0, stream,
                       QfA, KfI, VfI, offs_a, gsrc_a, glw_a, scbuf, msgA_h, msgA_l, A);
    hipLaunchKernelGGL(fused_attn, dim3((I + 3) / 4), dim3(256), 0, stream,
                       QfI, KfA, VfA, offs_i, gsrc_i, glw_i, scbuf, msgI_h, msgI_l, I);

    // ---- phase 2: fused hid->out ----
    hipLaunchKernelGGL((fused_node<1>), dim3(RBA), dim3(256), 32768, stream,
                       astP_h, astP_l, msgA_h, msgA_l,
                       wph[5], wpl[5],  // u_w1
                       wph[6], wpl[6],  // u_w2
                       (const unsigned short*)nullptr, (const unsigned short*)nullptr,
                       (const unsigned short*)nullptr, (const unsigned short*)nullptr,
                       (const unsigned short*)nullptr, (const unsigned short*)nullptr,
                       u_b1, u_b2, A, (float*)nullptr, (float*)nullptr, out_asset);
    hipLaunchKernelGGL((fused_node<1>), dim3(RBI), dim3(256), 32768, stream,
                       invP_h, invP_l, msgI_h, msgI_l,
                       wph[5], wpl[5], wph[6], wpl[6],
                       (const unsigned short*)nullptr, (const unsigned short*)nullptr,
                       (const unsigned short*)nullptr, (const unsigned short*)nullptr,
                       (const unsigned short*)nullptr, (const unsigned short*)nullptr,
                       u_b1, u_b2, I, (float*)nullptr, (float*)nullptr, out_inv);
}